// Round 5
// baseline (559.627 us; speedup 1.0000x reference)
//
#include <hip/hip_runtime.h>
#include <cmath>

// ---------------------------------------------------------------------------
// Poincare transformer layer. Round 5: split-K=4 on o-proj and f2 (4 blocks/CU
// co-residency; deterministic f32 partials summed in the mobius epilogue,
// d_out doubles as 4th partial), bf16 qkv outputs + bf16 headsplit chain.
// ---------------------------------------------------------------------------

constexpr int kD  = 1024;
constexpr int kH  = 16;
constexpr int kHD = 64;
constexpr int kFF = 4096;
constexpr int kB  = 4;
constexpr int kS  = 1024;
constexpr int kN  = kB * kS;   // 4096 tokens

#define EPSF 1e-7f
#define MTAF (1.0f - 1e-5f)

typedef unsigned int uint32;
typedef unsigned short ushort16;
typedef __attribute__((ext_vector_type(8))) short short8x;
typedef __attribute__((ext_vector_type(4))) float floatx4;

// ---------------- bf16 helpers ----------------
__device__ __forceinline__ ushort16 f2b(float f) {
  union { float f; uint32 u; } x; x.f = f;
  uint32 r = x.u + 0x7fffu + ((x.u >> 16) & 1u);   // RNE
  return (ushort16)(r >> 16);
}
__device__ __forceinline__ float b2f(ushort16 u) {
  union { uint32 u; float f; } x; x.u = ((uint32)u) << 16;
  return x.f;
}

// ---------------- math helpers ----------------
__device__ __forceinline__ float atanh_clipped(float n) {
  float c = fminf(n, MTAF);
  return 0.5f * logf((1.0f + c) / (1.0f - c));
}
__device__ __forceinline__ float logmap0_scale(float nraw) {
  float n = fmaxf(nraw, EPSF);
  return atanh_clipped(n) / n;
}
__device__ __forceinline__ float expmap0_scale(float nraw) {
  float n = fmaxf(nraw, EPSF);
  return tanhf(n) / n;
}
__device__ __forceinline__ float roundtrip_scale(float nraw) {
  float nu = fmaxf(nraw, EPSF);
  float se = tanhf(nu) / nu;
  float nb = fmaxf(se * nraw, EPSF);
  float sl = atanh_clipped(nb) / nb;
  return sl * se;
}

// ---------------- reductions ----------------
__device__ __forceinline__ float blockReduceSum256(float v, float* s4) {
#pragma unroll
  for (int o = 32; o > 0; o >>= 1) v += __shfl_xor(v, o);
  int wave = threadIdx.x >> 6;
  if ((threadIdx.x & 63) == 0) s4[wave] = v;
  __syncthreads();
  float r = s4[0] + s4[1] + s4[2] + s4[3];
  __syncthreads();
  return r;
}
__device__ __forceinline__ float waveReduceSum64(float v) {
#pragma unroll
  for (int o = 32; o > 0; o >>= 1) v += __shfl_xor(v, o);
  return v;
}
__device__ __forceinline__ float redSum16(float v) {
#pragma unroll
  for (int o = 8; o > 0; o >>= 1) v += __shfl_xor(v, o);
  return v;
}
__device__ __forceinline__ float redMax16(float v) {
#pragma unroll
  for (int o = 8; o > 0; o >>= 1) v = fmaxf(v, __shfl_xor(v, o));
  return v;
}

// ---------------- async global->LDS, 16 bytes/lane ----------------
__device__ __forceinline__ void async16(const void* g, void* l) {
  __builtin_amdgcn_global_load_lds(
      (const __attribute__((address_space(1))) uint32*)g,
      (__attribute__((address_space(3))) uint32*)l, 16, 0, 0);
}

// ---------------- weight transpose + cast: src [K][N] f32 -> dst [N][K] bf16 ----
__global__ __launch_bounds__(256) void k_transpose_bf16(const float* __restrict__ src,
                                                        ushort16* __restrict__ dst,
                                                        int K, int N) {
  __shared__ float T[64][65];
  int n0 = blockIdx.x * 64, k0 = blockIdx.y * 64;
#pragma unroll
  for (int p = 0; p < 16; ++p) {
    int idx = p * 256 + threadIdx.x;
    int r = idx >> 6, c = idx & 63;
    T[r][c] = src[(size_t)(k0 + r) * N + n0 + c];
  }
  __syncthreads();
#pragma unroll
  for (int p = 0; p < 16; ++p) {
    int idx = p * 256 + threadIdx.x;
    int r = idx >> 6, c = idx & 63;   // r: n-local, c: k-local
    dst[(size_t)(n0 + r) * K + k0 + c] = f2b(T[c][r]);
  }
}

// ---------------- ada = t_emb @ w_ada + b_ada ----------------
__global__ __launch_bounds__(256) void k_ada(const float* __restrict__ t_emb,
                                             const float* __restrict__ w_ada,
                                             const float* __restrict__ b_ada,
                                             float* __restrict__ ada) {
  __shared__ float te[kD];
  int b = blockIdx.y;
  for (int i = threadIdx.x; i < kD; i += 256) te[i] = t_emb[b * kD + i];
  __syncthreads();
  int col = blockIdx.x * 256 + threadIdx.x;
  float acc = b_ada[col];
  for (int k = 0; k < kD; ++k) acc += te[k] * w_ada[(size_t)k * (6 * kD) + col];
  ada[b * 6 * kD + col] = acc;
}

// ---------------- prenorm -> bf16 GEMM input ----------------
__global__ __launch_bounds__(256) void k_prenorm(const float* __restrict__ x,
                                                 const float* __restrict__ ada,
                                                 int sh_off, int sc_off,
                                                 ushort16* __restrict__ out) {
  __shared__ float sred[4];
  int tok = blockIdx.x;
  int b = tok >> 10;
  const float* xp = x + (size_t)tok * kD;
  float xv[4];
  float ss = 0.f;
#pragma unroll
  for (int i = 0; i < 4; ++i) {
    xv[i] = xp[i * 256 + threadIdx.x];
    ss += xv[i] * xv[i];
  }
  ss = blockReduceSum256(ss, sred);
  float sl = logmap0_scale(sqrtf(ss));
  float sum = 0.f;
#pragma unroll
  for (int i = 0; i < 4; ++i) { xv[i] *= sl; sum += xv[i]; }
  sum = blockReduceSum256(sum, sred);
  float mean = sum * (1.0f / kD);
  float vs = 0.f;
#pragma unroll
  for (int i = 0; i < 4; ++i) { xv[i] -= mean; vs += xv[i] * xv[i]; }
  vs = blockReduceSum256(vs, sred);
  float inv = rsqrtf(vs * (1.0f / kD) + 1e-6f);
  const float* shp = ada + b * 6 * kD + sh_off;
  const float* scp = ada + b * 6 * kD + sc_off;
  float uu = 0.f;
#pragma unroll
  for (int i = 0; i < 4; ++i) {
    int d = i * 256 + threadIdx.x;
    float u = xv[i] * inv * (1.0f + scp[d]) + shp[d];
    xv[i] = u;
    uu += u * u;
  }
  uu = blockReduceSum256(uu, sred);
  float s = roundtrip_scale(sqrtf(uu));
  ushort16* op = out + (size_t)tok * kD;
#pragma unroll
  for (int i = 0; i < 4; ++i) op[i * 256 + threadIdx.x] = f2b(s * xv[i]);
}

// ---------------- bf16 MFMA GEMM: C = A @ Bt^T + bias ----------------
// KSPLIT==1: blockIdx.z selects (Bt,bias,C) triple (merged qkv).
// KSPLIT>1 : blockIdx.z selects K-chunk; C[z] gets the partial; bias on z==0.
template <int OUT_BF16, int KSPLIT>
__global__ __launch_bounds__(256) void k_gemm_bf16(
    const ushort16* __restrict__ A,
    const ushort16* __restrict__ Bt0, const ushort16* __restrict__ Bt1,
    const ushort16* __restrict__ Bt2,
    const float* __restrict__ bias0, const float* __restrict__ bias1,
    const float* __restrict__ bias2,
    void* __restrict__ C0, void* __restrict__ C1, void* __restrict__ C2,
    void* __restrict__ C3,
    int M, int N, int K) {
  const ushort16* Bt;
  const float* bias;
  void* C;
  int k_lo, k_hi;
  bool add_bias;
  if (KSPLIT == 1) {
    Bt = (blockIdx.z == 0) ? Bt0 : ((blockIdx.z == 1) ? Bt1 : Bt2);
    bias = (blockIdx.z == 0) ? bias0 : ((blockIdx.z == 1) ? bias1 : bias2);
    C = (blockIdx.z == 0) ? C0 : ((blockIdx.z == 1) ? C1 : C2);
    k_lo = 0; k_hi = K; add_bias = true;
  } else {
    Bt = Bt0; bias = bias0;
    C = (blockIdx.z == 0) ? C0 : ((blockIdx.z == 1) ? C1 :
        ((blockIdx.z == 2) ? C2 : C3));
    int kchunk = K / KSPLIT;
    k_lo = blockIdx.z * kchunk; k_hi = k_lo + kchunk;
    add_bias = (blockIdx.z == 0);
  }

  __shared__ __align__(16) ushort16 As[128 * 32];
  __shared__ __align__(16) ushort16 Bs[128 * 32];

  int tid = threadIdx.x;
  int lane = tid & 63;
  int wave = tid >> 6;
  int wm = (wave >> 1) * 64, wn = (wave & 1) * 64;
  int row0 = blockIdx.y * 128, col0 = blockIdx.x * 128;

  int e0 = tid * 8;
  int ar0 = e0 >> 5, ac0 = e0 & 31;
  int e1 = e0 + 2048;
  int ar1 = e1 >> 5, ac1 = e1 & 31;
  const ushort16* Ag = A + (size_t)row0 * K;
  const ushort16* Bg = Bt + (size_t)col0 * K;

  floatx4 acc[4][4];
#pragma unroll
  for (int i = 0; i < 4; ++i)
#pragma unroll
    for (int j = 0; j < 4; ++j) acc[i][j] = (floatx4)0.f;

  for (int k0 = k_lo; k0 < k_hi; k0 += 32) {
    async16(Ag + (size_t)ar0 * K + k0 + ac0, As + e0);
    async16(Ag + (size_t)ar1 * K + k0 + ac1, As + e1);
    async16(Bg + (size_t)ar0 * K + k0 + ac0, Bs + e0);
    async16(Bg + (size_t)ar1 * K + k0 + ac1, Bs + e1);
    __syncthreads();

    short8x a[4], b[4];
#pragma unroll
    for (int i = 0; i < 4; ++i) {
      a[i] = *(const short8x*)&As[(wm + i * 16 + (lane & 15)) * 32 + (lane >> 4) * 8];
      b[i] = *(const short8x*)&Bs[(wn + i * 16 + (lane & 15)) * 32 + (lane >> 4) * 8];
    }
#pragma unroll
    for (int i = 0; i < 4; ++i)
#pragma unroll
      for (int j = 0; j < 4; ++j)
        acc[i][j] = __builtin_amdgcn_mfma_f32_16x16x32_bf16(a[i], b[j], acc[i][j], 0, 0, 0);
    __syncthreads();
  }

  float bv[4];
#pragma unroll
  for (int j = 0; j < 4; ++j)
    bv[j] = add_bias ? bias[col0 + wn + j * 16 + (lane & 15)] : 0.f;
  int rowq = (lane >> 4) * 4;
#pragma unroll
  for (int i = 0; i < 4; ++i) {
    int rbase = row0 + wm + i * 16 + rowq;
#pragma unroll
    for (int j = 0; j < 4; ++j) {
      int c = col0 + wn + j * 16 + (lane & 15);
#pragma unroll
      for (int r = 0; r < 4; ++r) {
        float v = acc[i][j][r] + bv[j];
        if (OUT_BF16)
          ((ushort16*)C)[(size_t)(rbase + r) * N + c] = f2b(v);
        else
          ((float*)C)[(size_t)(rbase + r) * N + c] = v;
      }
    }
  }
}

// ---------------- head split, all-bf16: q->qb_out (pre-scaled 1/8),
// k,v scaled IN PLACE. Folds _to_heads + logmap0 scales. ----------------
__global__ __launch_bounds__(256) void k_headsplit_b(const ushort16* __restrict__ q_in,
                                                     ushort16* __restrict__ k_io,
                                                     ushort16* __restrict__ v_io,
                                                     ushort16* __restrict__ qb_out,
                                                     float ratio) {
  __shared__ float sh[16];
  int tok = blockIdx.x;
  int tid = threadIdx.x, wave = tid >> 6;
#pragma unroll
  for (int t = 0; t < 3; ++t) {
    const ushort16* p = (t == 0 ? q_in : (t == 1 ? (const ushort16*)k_io
                                                 : (const ushort16*)v_io)) +
                        (size_t)tok * kD;
    float val[4], hs[4];
#pragma unroll
    for (int i = 0; i < 4; ++i) {
      val[i] = b2f(p[i * 256 + tid]);
      hs[i] = waveReduceSum64(val[i] * val[i]);  // head (i*4 + wave) sumsq
    }
    if ((tid & 63) == 0) {
#pragma unroll
      for (int i = 0; i < 4; ++i) sh[i * 4 + wave] = hs[i];
    }
    __syncthreads();
    float tot = 0.f;
#pragma unroll
    for (int j = 0; j < 16; ++j) tot += sh[j];
    float s1 = roundtrip_scale(sqrtf(tot));
    float c = s1 * ratio;
    ushort16* op = (t == 0 ? qb_out : (t == 1 ? k_io : v_io)) + (size_t)tok * kD;
#pragma unroll
    for (int i = 0; i < 4; ++i) {
      float m = c * sqrtf(hs[i]);
      float s2 = roundtrip_scale(m);
      float ov = c * s2 * val[i];
      op[i * 256 + tid] = f2b(t == 0 ? 0.125f * ov : ov);  // fold 1/sqrt(HD) into q
    }
    __syncthreads();
  }
}

// ---------------- V transpose: v bf16 [N][D] -> vT bf16 [B*H][64][S] ----------------
__global__ __launch_bounds__(256) void k_vtrans_b(const ushort16* __restrict__ v,
                                                  ushort16* __restrict__ vT) {
  __shared__ ushort16 T[64][68];
  int bh = blockIdx.y, b = bh >> 4, h = bh & 15;
  int s0 = blockIdx.x * 64;
  int tid = threadIdx.x;
#pragma unroll
  for (int p = 0; p < 16; ++p) {
    int idx = p * 256 + tid;
    int r = idx >> 6, d = idx & 63;
    T[r][d] = v[(size_t)(b * kS + s0 + r) * kD + h * kHD + d];
  }
  __syncthreads();
#pragma unroll
  for (int p = 0; p < 16; ++p) {
    int idx = p * 256 + tid;
    int d = idx >> 6, c = idx & 63;
    vT[((size_t)bh * kHD + d) * kS + s0 + c] = T[c][d];
  }
}

// ---------------- MFMA flash attention ----------------
__global__ __launch_bounds__(256) void k_attn_mfma(const ushort16* __restrict__ qb,
                                                   const ushort16* __restrict__ kb,
                                                   const ushort16* __restrict__ vT,
                                                   float* __restrict__ outp,
                                                   float ratio2) {
  __shared__ __align__(16) ushort16 Ks[2 * 128 * 32];   // [ksub(d)][key][32]
  __shared__ __align__(16) ushort16 Vs[4 * 64 * 32];    // [ssub][d][32]
  __shared__ __align__(16) ushort16 Ps[4 * 4 * 16 * 32];// [wave][ksub(s)][row16][32]
  int bh = blockIdx.y, b = bh >> 4, h = bh & 15;
  int q0 = blockIdx.x * 128;
  int tid = threadIdx.x, lane = tid & 63, wave = tid >> 6;
  int c16 = lane & 15, quad = lane >> 4;
  int wq = wave * 32;

  short8x a_q[2][2];
#pragma unroll
  for (int i = 0; i < 2; ++i)
#pragma unroll
    for (int kk = 0; kk < 2; ++kk)
      a_q[i][kk] = *(const short8x*)&qb[(size_t)(b * kS + q0 + wq + i * 16 + c16) * kD +
                                        h * kHD + kk * 32 + quad * 8];

  float m_i[2][4], l_i[2][4];
  floatx4 o[2][4];
#pragma unroll
  for (int i = 0; i < 2; ++i)
#pragma unroll
    for (int r = 0; r < 4; ++r) { m_i[i][r] = -INFINITY; l_i[i][r] = 0.f; }
#pragma unroll
  for (int i = 0; i < 2; ++i)
#pragma unroll
    for (int n = 0; n < 4; ++n) o[i][n] = (floatx4)0.f;

  const ushort16* kbase = kb + ((size_t)b * kS) * kD + h * kHD;
  const ushort16* vbase = vT + (size_t)bh * kHD * kS;

  for (int k0 = 0; k0 < kS; k0 += 128) {
#pragma unroll
    for (int t = 0; t < 2; ++t)
#pragma unroll
      for (int cb = 0; cb < 2; ++cb) {
        int e = cb * 2048 + tid * 8;
        async16(kbase + (size_t)(k0 + (e >> 5)) * kD + t * 32 + (e & 31),
                Ks + t * 4096 + e);
      }
#pragma unroll
    for (int t = 0; t < 4; ++t) {
      int e = tid * 8;
      async16(vbase + (size_t)(e >> 5) * kS + k0 + t * 32 + (e & 31),
              Vs + t * 2048 + e);
    }
    __syncthreads();

#pragma unroll
    for (int i = 0; i < 2; ++i) {
      floatx4 s[8];
#pragma unroll
      for (int n = 0; n < 8; ++n) s[n] = (floatx4)0.f;
#pragma unroll
      for (int kkd = 0; kkd < 2; ++kkd)
#pragma unroll
        for (int n = 0; n < 8; ++n) {
          short8x bk = *(const short8x*)&Ks[kkd * 4096 + (n * 16 + c16) * 32 + quad * 8];
          s[n] = __builtin_amdgcn_mfma_f32_16x16x32_bf16(a_q[i][kkd], bk, s[n], 0, 0, 0);
        }

#pragma unroll
      for (int r = 0; r < 4; ++r) {
        float mx = s[0][r];
#pragma unroll
        for (int n = 1; n < 8; ++n) mx = fmaxf(mx, s[n][r]);
        mx = redMax16(mx);
        float mold = m_i[i][r];
        float mnew = fmaxf(mold, mx);
        float alpha = __expf(mold - mnew);
        m_i[i][r] = mnew;
        float rs = 0.f;
#pragma unroll
        for (int n = 0; n < 8; ++n) {
          float pp = __expf(s[n][r] - mnew);
          ushort16 pbv = f2b(pp);
          rs += b2f(pbv);
          Ps[(wave * 4 + (n >> 1)) * 512 + (quad * 4 + r) * 32 + (n & 1) * 16 + c16] = pbv;
        }
        rs = redSum16(rs);
        l_i[i][r] = l_i[i][r] * alpha + rs;
#pragma unroll
        for (int n = 0; n < 4; ++n) o[i][n][r] *= alpha;
      }

#pragma unroll
      for (int kk = 0; kk < 4; ++kk) {
        short8x ap = *(const short8x*)&Ps[(wave * 4 + kk) * 512 + c16 * 32 + quad * 8];
#pragma unroll
        for (int n = 0; n < 4; ++n) {
          short8x bv = *(const short8x*)&Vs[kk * 2048 + (n * 16 + c16) * 32 + quad * 8];
          o[i][n] = __builtin_amdgcn_mfma_f32_16x16x32_bf16(ap, bv, o[i][n], 0, 0, 0);
        }
      }
    }
    __syncthreads();
  }

#pragma unroll
  for (int i = 0; i < 2; ++i)
#pragma unroll
    for (int r = 0; r < 4; ++r) {
      float invl = 1.0f / l_i[i][r];
      float w[4];
      float pssq = 0.f;
#pragma unroll
      for (int n = 0; n < 4; ++n) { w[n] = o[i][n][r] * invl; pssq += w[n] * w[n]; }
      float ssq = redSum16(pssq);
      float coef = roundtrip_scale(sqrtf(ssq)) * ratio2;
      int row = b * kS + q0 + wq + i * 16 + quad * 4 + r;
#pragma unroll
      for (int n = 0; n < 4; ++n)
        outp[(size_t)row * kD + h * kHD + n * 16 + c16] = coef * w[n];
    }
}

// ---------------- roundtrip scale, fp32 in -> bf16 out ----------------
template <int WIDTH>
__global__ __launch_bounds__(256) void k_rt_scale_f2b(const float* __restrict__ p,
                                                      ushort16* __restrict__ out) {
  __shared__ float sred[4];
  constexpr int PER = WIDTH / 256;
  size_t base = (size_t)blockIdx.x * WIDTH;
  float v[PER];
  float ss = 0.f;
#pragma unroll
  for (int i = 0; i < PER; ++i) {
    v[i] = p[base + i * 256 + threadIdx.x];
    ss += v[i] * v[i];
  }
  ss = blockReduceSum256(ss, sred);
  float s = roundtrip_scale(sqrtf(ss));
#pragma unroll
  for (int i = 0; i < PER; ++i) out[base + i * 256 + threadIdx.x] = f2b(s * v[i]);
}

// ---------------- roundtrip scale, bf16 in/out (in place) ----------------
template <int WIDTH>
__global__ __launch_bounds__(256) void k_rt_scale_b2b(ushort16* __restrict__ p) {
  __shared__ float sred[4];
  constexpr int PER = WIDTH / 256;
  size_t base = (size_t)blockIdx.x * WIDTH;
  float v[PER];
  float ss = 0.f;
#pragma unroll
  for (int i = 0; i < PER; ++i) {
    v[i] = b2f(p[base + i * 256 + threadIdx.x]);
    ss += v[i] * v[i];
  }
  ss = blockReduceSum256(ss, sred);
  float s = roundtrip_scale(sqrtf(ss));
#pragma unroll
  for (int i = 0; i < PER; ++i) p[base + i * 256 + threadIdx.x] = f2b(s * v[i]);
}

// ---------------- mobius epilogue; ot = p0+p1+p2+p3 (split-K=4 partials) ----------------
__global__ __launch_bounds__(256) void k_epilogue4(const float* __restrict__ xres,
                                                   const float* __restrict__ p0,
                                                   const float* __restrict__ p1,
                                                   const float* __restrict__ p2,
                                                   const float* __restrict__ p3,
                                                   const float* __restrict__ ada,
                                                   int g_off,
                                                   float* __restrict__ out) {
  __shared__ float sred[4];
  int tok = blockIdx.x;
  int b = tok >> 10;
  size_t base = (size_t)tok * kD;
  float xv[4], tv[4];
  float ss = 0.f;
#pragma unroll
  for (int i = 0; i < 4; ++i) {
    int d = i * 256 + threadIdx.x;
    tv[i] = (p0[base + d] + p1[base + d]) + (p2[base + d] + p3[base + d]);
    xv[i] = xres[base + d];
    ss += tv[i] * tv[i];
  }
  ss = blockReduceSum256(ss, sred);
  float s5 = roundtrip_scale(sqrtf(ss));
  const float* gp = ada + b * 6 * kD + g_off;
  float at2 = 0.f;
#pragma unroll
  for (int i = 0; i < 4; ++i) {
    float a = gp[i * 256 + threadIdx.x] * s5 * tv[i];
    tv[i] = a;
    at2 += a * a;
  }
  at2 = blockReduceSum256(at2, sred);
  float nyraw = sqrtf(at2);
  float sy = expmap0_scale(nyraw);
  float ynorm = sy * nyraw;
  float y2 = ynorm * ynorm;
  float x2p = 0.f, xyp = 0.f;
#pragma unroll
  for (int i = 0; i < 4; ++i) {
    float y = sy * tv[i];
    tv[i] = y;
    x2p += xv[i] * xv[i];
    xyp += xv[i] * y;
  }
  float x2 = blockReduceSum256(x2p, sred);
  float xy = blockReduceSum256(xyp, sred);
  float cx = 1.0f + 2.0f * xy + y2;
  float cy = 1.0f - x2;
  float den = fmaxf(1.0f + 2.0f * xy + x2 * y2, EPSF);
  float invden = 1.0f / den;
#pragma unroll
  for (int i = 0; i < 4; ++i)
    out[base + i * 256 + threadIdx.x] = (cx * xv[i] + cy * tv[i]) * invden;
}

// ---------------------------------------------------------------------------
extern "C" void kernel_launch(void* const* d_in, const int* in_sizes, int n_in,
                              void* d_out, int out_size, void* d_ws, size_t ws_size,
                              hipStream_t stream) {
  const float* x     = (const float*)d_in[0];
  const float* t_emb = (const float*)d_in[1];
  const float* w_q = (const float*)d_in[2];  const float* b_q = (const float*)d_in[3];
  const float* w_k = (const float*)d_in[4];  const float* b_k = (const float*)d_in[5];
  const float* w_v = (const float*)d_in[6];  const float* b_v = (const float*)d_in[7];
  const float* w_o = (const float*)d_in[8];  const float* b_o = (const float*)d_in[9];
  const float* w_f1 = (const float*)d_in[10]; const float* b_f1 = (const float*)d_in[11];
  const float* w_f2 = (const float*)d_in[12]; const float* b_f2 = (const float*)d_in[13];
  const float* w_ada = (const float*)d_in[14]; const float* b_ada = (const float*)d_in[15];
  float* out = (float*)d_out;

  constexpr size_t ND = (size_t)kN * kD;    // 4 M
  constexpr size_t NF = (size_t)kN * kFF;   // 16 M
  constexpr size_t DD = (size_t)kD * kD;    // 1 M

  float* ws   = (float*)d_ws;
  float* ada  = ws;                 // 24576 f32
  float* qt   = ada + 6 * kD * kB;  // ND f32 (split-K partial 0)
  float* kt   = qt + ND;            // ND f32 (attn out; split-K partial 1)
  float* vt   = kt + ND;            // ND f32 (o-partial 2 -> x_mid in place)
  ushort16* qbA = (ushort16*)(vt + ND);   // ND bf16 (lx / qb / rt(ao) / lx2)
  ushort16* kb  = qbA + ND;               // ND bf16 (q raw -> vT)
  ushort16* vTb = kb + ND;                // ND bf16 (k raw -> k scaled)
  ushort16* actB = vTb + ND;              // NF bf16 (v raw/scaled in slab 0; h1)
  ushort16* wqT  = actB + NF;             // DD bf16 each
  ushort16* wkT  = wqT + DD;
  ushort16* wvT  = wkT + DD;
  ushort16* woT  = wvT + DD;
  ushort16* wf1T = woT + DD;              // FF*D
  ushort16* wf2T = wf1T + (size_t)kD * kFF;
  float* partA = (float*)qbA;             // 16 MB f32 region over qbA+kb (f2 partial 2)

  double bn = exp(lgamma(512.0) + lgamma(0.5) - lgamma(512.5));
  double bh = exp(lgamma(32.0) + lgamma(0.5) - lgamma(32.5));
  float R1 = (float)(bh / bn);
  float R2 = (float)(bn / bh);

  // 0) weight transpose + cast to bf16 [N][K]
  k_transpose_bf16<<<dim3(16, 16), 256, 0, stream>>>(w_q, wqT, kD, kD);
  k_transpose_bf16<<<dim3(16, 16), 256, 0, stream>>>(w_k, wkT, kD, kD);
  k_transpose_bf16<<<dim3(16, 16), 256, 0, stream>>>(w_v, wvT, kD, kD);
  k_transpose_bf16<<<dim3(16, 16), 256, 0, stream>>>(w_o, woT, kD, kD);
  k_transpose_bf16<<<dim3(64, 16), 256, 0, stream>>>(w_f1, wf1T, kD, kFF);
  k_transpose_bf16<<<dim3(16, 64), 256, 0, stream>>>(w_f2, wf2T, kFF, kD);
  // 1) ada
  k_ada<<<dim3(6 * kD / 256, kB), 256, 0, stream>>>(t_emb, w_ada, b_ada, ada);
  // 2) prenorm (msa): lx -> qbA (bf16)
  k_prenorm<<<kN, 256, 0, stream>>>(x, ada, 0 * kD, 1 * kD, qbA);
  // 3) q,k,v projections, bf16 out: q->kb, k->vTb, v->actB (768 blocks)
  k_gemm_bf16<1, 1><<<dim3(kD / 128, kN / 128, 3), 256, 0, stream>>>(
      qbA, wqT, wkT, wvT, b_q, b_k, b_v, kb, vTb, actB, nullptr, kN, kD, kD);
  // 4) head split (bf16): qb->qbA (pre-scaled 1/8), k scaled in vTb, v scaled in actB
  k_headsplit_b<<<kN, 256, 0, stream>>>(kb, vTb, actB, qbA, R1);
  // 5) V transpose: actB -> kb ([B*H][64][S] bf16)
  k_vtrans_b<<<dim3(kS / 64, kB * kH), 256, 0, stream>>>(actB, kb);
  // 6) MFMA flash attention -> kt (f32 tangent, per-head scaled)
  k_attn_mfma<<<dim3(kS / 128, kB * kH), 256, 0, stream>>>(qbA, vTb, kb, kt, R2);
  // 7) full-dim roundtrip -> qbA (bf16)
  k_rt_scale_f2b<kD><<<kN, 256, 0, stream>>>(kt, qbA);
  // 8) o projection, split-K=4 -> partials qt(+bias), kt, vt, out (1024 blocks)
  k_gemm_bf16<0, 4><<<dim3(kD / 128, kN / 128, 4), 256, 0, stream>>>(
      qbA, woT, woT, woT, b_o, b_o, b_o, qt, kt, vt, out, kN, kD, kD);
  // 9) mobius epilogue (msa): x_mid = mobius(x, sum partials) -> vt (in-place safe)
  k_epilogue4<<<kN, 256, 0, stream>>>(x, qt, kt, vt, out, ada, 2 * kD, vt);
  // 10) prenorm (mlp): lx2 -> qbA (bf16)
  k_prenorm<<<kN, 256, 0, stream>>>(vt, ada, 3 * kD, 4 * kD, qbA);
  // 11) f1 -> actB (bf16 direct; 1024 blocks)
  k_gemm_bf16<1, 1><<<dim3(kFF / 128, kN / 128, 1), 256, 0, stream>>>(
      qbA, wf1T, wf1T, wf1T, b_f1, b_f1, b_f1, actB, actB, actB, nullptr, kN, kFF, kD);
  // 12) roundtrip on h1 (bf16 in place)
  k_rt_scale_b2b<kFF><<<kN, 256, 0, stream>>>(actB);
  // 13) f2, split-K=4 -> partials qt(+bias), kt, partA(=qbA/kb region), out (1024 blocks)
  k_gemm_bf16<0, 4><<<dim3(kD / 128, kN / 128, 4), 256, 0, stream>>>(
      actB, wf2T, wf2T, wf2T, b_f2, b_f2, b_f2, qt, kt, partA, out, kN, kD, kFF);
  // 14) mobius epilogue (mlp): out = mobius(vt, sum partials) (in-place safe)
  k_epilogue4<<<kN, 256, 0, stream>>>(vt, qt, kt, partA, out, ada, 5 * kD, out);

  (void)in_sizes; (void)n_in; (void)out_size; (void)ws_size;
}

// Round 6
// 537.787 us; speedup vs baseline: 1.0406x; 1.0406x over previous
//
#include <hip/hip_runtime.h>
#include <cmath>

// ---------------------------------------------------------------------------
// Poincare transformer layer. Round 6: revert to split-K=2 (round-4 proven);
// keep bf16 qkv chain (round 5); NEW: grid-dim swap on all big GEMMs so
// row-tiles ride blockIdx.x -> XCD = row%8 -> per-XCD A working set (<=2 MB)
// stays L2-resident while B streams via L3. (Old layout put a whole column
// on one XCD, streaming all of A through a 4 MB L2 -> 3.4x refetch.)
// ---------------------------------------------------------------------------

constexpr int kD  = 1024;
constexpr int kH  = 16;
constexpr int kHD = 64;
constexpr int kFF = 4096;
constexpr int kB  = 4;
constexpr int kS  = 1024;
constexpr int kN  = kB * kS;   // 4096 tokens

#define EPSF 1e-7f
#define MTAF (1.0f - 1e-5f)

typedef unsigned int uint32;
typedef unsigned short ushort16;
typedef __attribute__((ext_vector_type(8))) short short8x;
typedef __attribute__((ext_vector_type(4))) float floatx4;

// ---------------- bf16 helpers ----------------
__device__ __forceinline__ ushort16 f2b(float f) {
  union { float f; uint32 u; } x; x.f = f;
  uint32 r = x.u + 0x7fffu + ((x.u >> 16) & 1u);   // RNE
  return (ushort16)(r >> 16);
}
__device__ __forceinline__ float b2f(ushort16 u) {
  union { uint32 u; float f; } x; x.u = ((uint32)u) << 16;
  return x.f;
}

// ---------------- math helpers ----------------
__device__ __forceinline__ float atanh_clipped(float n) {
  float c = fminf(n, MTAF);
  return 0.5f * logf((1.0f + c) / (1.0f - c));
}
__device__ __forceinline__ float logmap0_scale(float nraw) {
  float n = fmaxf(nraw, EPSF);
  return atanh_clipped(n) / n;
}
__device__ __forceinline__ float expmap0_scale(float nraw) {
  float n = fmaxf(nraw, EPSF);
  return tanhf(n) / n;
}
__device__ __forceinline__ float roundtrip_scale(float nraw) {
  float nu = fmaxf(nraw, EPSF);
  float se = tanhf(nu) / nu;
  float nb = fmaxf(se * nraw, EPSF);
  float sl = atanh_clipped(nb) / nb;
  return sl * se;
}

// ---------------- reductions ----------------
__device__ __forceinline__ float blockReduceSum256(float v, float* s4) {
#pragma unroll
  for (int o = 32; o > 0; o >>= 1) v += __shfl_xor(v, o);
  int wave = threadIdx.x >> 6;
  if ((threadIdx.x & 63) == 0) s4[wave] = v;
  __syncthreads();
  float r = s4[0] + s4[1] + s4[2] + s4[3];
  __syncthreads();
  return r;
}
__device__ __forceinline__ float waveReduceSum64(float v) {
#pragma unroll
  for (int o = 32; o > 0; o >>= 1) v += __shfl_xor(v, o);
  return v;
}
__device__ __forceinline__ float redSum16(float v) {
#pragma unroll
  for (int o = 8; o > 0; o >>= 1) v += __shfl_xor(v, o);
  return v;
}
__device__ __forceinline__ float redMax16(float v) {
#pragma unroll
  for (int o = 8; o > 0; o >>= 1) v = fmaxf(v, __shfl_xor(v, o));
  return v;
}

// ---------------- async global->LDS, 16 bytes/lane ----------------
__device__ __forceinline__ void async16(const void* g, void* l) {
  __builtin_amdgcn_global_load_lds(
      (const __attribute__((address_space(1))) uint32*)g,
      (__attribute__((address_space(3))) uint32*)l, 16, 0, 0);
}

// ---------------- weight transpose + cast: src [K][N] f32 -> dst [N][K] bf16 ----
__global__ __launch_bounds__(256) void k_transpose_bf16(const float* __restrict__ src,
                                                        ushort16* __restrict__ dst,
                                                        int K, int N) {
  __shared__ float T[64][65];
  int n0 = blockIdx.x * 64, k0 = blockIdx.y * 64;
#pragma unroll
  for (int p = 0; p < 16; ++p) {
    int idx = p * 256 + threadIdx.x;
    int r = idx >> 6, c = idx & 63;
    T[r][c] = src[(size_t)(k0 + r) * N + n0 + c];
  }
  __syncthreads();
#pragma unroll
  for (int p = 0; p < 16; ++p) {
    int idx = p * 256 + threadIdx.x;
    int r = idx >> 6, c = idx & 63;   // r: n-local, c: k-local
    dst[(size_t)(n0 + r) * K + k0 + c] = f2b(T[c][r]);
  }
}

// ---------------- ada = t_emb @ w_ada + b_ada ----------------
__global__ __launch_bounds__(256) void k_ada(const float* __restrict__ t_emb,
                                             const float* __restrict__ w_ada,
                                             const float* __restrict__ b_ada,
                                             float* __restrict__ ada) {
  __shared__ float te[kD];
  int b = blockIdx.y;
  for (int i = threadIdx.x; i < kD; i += 256) te[i] = t_emb[b * kD + i];
  __syncthreads();
  int col = blockIdx.x * 256 + threadIdx.x;
  float acc = b_ada[col];
  for (int k = 0; k < kD; ++k) acc += te[k] * w_ada[(size_t)k * (6 * kD) + col];
  ada[b * 6 * kD + col] = acc;
}

// ---------------- prenorm -> bf16 GEMM input ----------------
__global__ __launch_bounds__(256) void k_prenorm(const float* __restrict__ x,
                                                 const float* __restrict__ ada,
                                                 int sh_off, int sc_off,
                                                 ushort16* __restrict__ out) {
  __shared__ float sred[4];
  int tok = blockIdx.x;
  int b = tok >> 10;
  const float* xp = x + (size_t)tok * kD;
  float xv[4];
  float ss = 0.f;
#pragma unroll
  for (int i = 0; i < 4; ++i) {
    xv[i] = xp[i * 256 + threadIdx.x];
    ss += xv[i] * xv[i];
  }
  ss = blockReduceSum256(ss, sred);
  float sl = logmap0_scale(sqrtf(ss));
  float sum = 0.f;
#pragma unroll
  for (int i = 0; i < 4; ++i) { xv[i] *= sl; sum += xv[i]; }
  sum = blockReduceSum256(sum, sred);
  float mean = sum * (1.0f / kD);
  float vs = 0.f;
#pragma unroll
  for (int i = 0; i < 4; ++i) { xv[i] -= mean; vs += xv[i] * xv[i]; }
  vs = blockReduceSum256(vs, sred);
  float inv = rsqrtf(vs * (1.0f / kD) + 1e-6f);
  const float* shp = ada + b * 6 * kD + sh_off;
  const float* scp = ada + b * 6 * kD + sc_off;
  float uu = 0.f;
#pragma unroll
  for (int i = 0; i < 4; ++i) {
    int d = i * 256 + threadIdx.x;
    float u = xv[i] * inv * (1.0f + scp[d]) + shp[d];
    xv[i] = u;
    uu += u * u;
  }
  uu = blockReduceSum256(uu, sred);
  float s = roundtrip_scale(sqrtf(uu));
  ushort16* op = out + (size_t)tok * kD;
#pragma unroll
  for (int i = 0; i < 4; ++i) op[i * 256 + threadIdx.x] = f2b(s * xv[i]);
}

// ---------------- bf16 MFMA GEMM: C = A @ Bt^T + bias ----------------
// GRID: (M/128, N/128, Z)  -- row tiles on blockIdx.x so XCD = row%8:
// per-XCD A working set stays L2-resident; B streams (L3-served).
// KSPLIT==1: blockIdx.z selects (Bt,bias,C) triple (merged qkv).
// KSPLIT==2: blockIdx.z selects K-half; z=0 -> C0 (with bias), z=1 -> C1.
template <int OUT_BF16, int KSPLIT>
__global__ __launch_bounds__(256) void k_gemm_bf16(
    const ushort16* __restrict__ A,
    const ushort16* __restrict__ Bt0, const ushort16* __restrict__ Bt1,
    const ushort16* __restrict__ Bt2,
    const float* __restrict__ bias0, const float* __restrict__ bias1,
    const float* __restrict__ bias2,
    void* __restrict__ C0, void* __restrict__ C1, void* __restrict__ C2,
    int M, int N, int K) {
  const ushort16* Bt;
  const float* bias;
  void* C;
  int k_lo, k_hi;
  bool add_bias;
  if (KSPLIT == 1) {
    Bt = (blockIdx.z == 0) ? Bt0 : ((blockIdx.z == 1) ? Bt1 : Bt2);
    bias = (blockIdx.z == 0) ? bias0 : ((blockIdx.z == 1) ? bias1 : bias2);
    C = (blockIdx.z == 0) ? C0 : ((blockIdx.z == 1) ? C1 : C2);
    k_lo = 0; k_hi = K; add_bias = true;
  } else {
    Bt = Bt0; bias = bias0;
    C = (blockIdx.z == 0) ? C0 : C1;
    int kchunk = K / KSPLIT;
    k_lo = blockIdx.z * kchunk; k_hi = k_lo + kchunk;
    add_bias = (blockIdx.z == 0);
  }

  __shared__ __align__(16) ushort16 As[128 * 32];
  __shared__ __align__(16) ushort16 Bs[128 * 32];

  int tid = threadIdx.x;
  int lane = tid & 63;
  int wave = tid >> 6;
  int wm = (wave >> 1) * 64, wn = (wave & 1) * 64;
  int row0 = blockIdx.x * 128, col0 = blockIdx.y * 128;   // swapped grid

  int e0 = tid * 8;
  int ar0 = e0 >> 5, ac0 = e0 & 31;
  int e1 = e0 + 2048;
  int ar1 = e1 >> 5, ac1 = e1 & 31;
  const ushort16* Ag = A + (size_t)row0 * K;
  const ushort16* Bg = Bt + (size_t)col0 * K;

  floatx4 acc[4][4];
#pragma unroll
  for (int i = 0; i < 4; ++i)
#pragma unroll
    for (int j = 0; j < 4; ++j) acc[i][j] = (floatx4)0.f;

  for (int k0 = k_lo; k0 < k_hi; k0 += 32) {
    async16(Ag + (size_t)ar0 * K + k0 + ac0, As + e0);
    async16(Ag + (size_t)ar1 * K + k0 + ac1, As + e1);
    async16(Bg + (size_t)ar0 * K + k0 + ac0, Bs + e0);
    async16(Bg + (size_t)ar1 * K + k0 + ac1, Bs + e1);
    __syncthreads();

    short8x a[4], b[4];
#pragma unroll
    for (int i = 0; i < 4; ++i) {
      a[i] = *(const short8x*)&As[(wm + i * 16 + (lane & 15)) * 32 + (lane >> 4) * 8];
      b[i] = *(const short8x*)&Bs[(wn + i * 16 + (lane & 15)) * 32 + (lane >> 4) * 8];
    }
#pragma unroll
    for (int i = 0; i < 4; ++i)
#pragma unroll
      for (int j = 0; j < 4; ++j)
        acc[i][j] = __builtin_amdgcn_mfma_f32_16x16x32_bf16(a[i], b[j], acc[i][j], 0, 0, 0);
    __syncthreads();
  }

  float bv[4];
#pragma unroll
  for (int j = 0; j < 4; ++j)
    bv[j] = add_bias ? bias[col0 + wn + j * 16 + (lane & 15)] : 0.f;
  int rowq = (lane >> 4) * 4;
#pragma unroll
  for (int i = 0; i < 4; ++i) {
    int rbase = row0 + wm + i * 16 + rowq;
#pragma unroll
    for (int j = 0; j < 4; ++j) {
      int c = col0 + wn + j * 16 + (lane & 15);
#pragma unroll
      for (int r = 0; r < 4; ++r) {
        float v = acc[i][j][r] + bv[j];
        if (OUT_BF16)
          ((ushort16*)C)[(size_t)(rbase + r) * N + c] = f2b(v);
        else
          ((float*)C)[(size_t)(rbase + r) * N + c] = v;
      }
    }
  }
}

// ---------------- head split, all-bf16: q->qb_out (pre-scaled 1/8),
// k,v scaled IN PLACE. Folds _to_heads + logmap0 scales. ----------------
__global__ __launch_bounds__(256) void k_headsplit_b(const ushort16* __restrict__ q_in,
                                                     ushort16* __restrict__ k_io,
                                                     ushort16* __restrict__ v_io,
                                                     ushort16* __restrict__ qb_out,
                                                     float ratio) {
  __shared__ float sh[16];
  int tok = blockIdx.x;
  int tid = threadIdx.x, wave = tid >> 6;
#pragma unroll
  for (int t = 0; t < 3; ++t) {
    const ushort16* p = (t == 0 ? q_in : (t == 1 ? (const ushort16*)k_io
                                                 : (const ushort16*)v_io)) +
                        (size_t)tok * kD;
    float val[4], hs[4];
#pragma unroll
    for (int i = 0; i < 4; ++i) {
      val[i] = b2f(p[i * 256 + tid]);
      hs[i] = waveReduceSum64(val[i] * val[i]);  // head (i*4 + wave) sumsq
    }
    if ((tid & 63) == 0) {
#pragma unroll
      for (int i = 0; i < 4; ++i) sh[i * 4 + wave] = hs[i];
    }
    __syncthreads();
    float tot = 0.f;
#pragma unroll
    for (int j = 0; j < 16; ++j) tot += sh[j];
    float s1 = roundtrip_scale(sqrtf(tot));
    float c = s1 * ratio;
    ushort16* op = (t == 0 ? qb_out : (t == 1 ? k_io : v_io)) + (size_t)tok * kD;
#pragma unroll
    for (int i = 0; i < 4; ++i) {
      float m = c * sqrtf(hs[i]);
      float s2 = roundtrip_scale(m);
      float ov = c * s2 * val[i];
      op[i * 256 + tid] = f2b(t == 0 ? 0.125f * ov : ov);  // fold 1/sqrt(HD) into q
    }
    __syncthreads();
  }
}

// ---------------- V transpose: v bf16 [N][D] -> vT bf16 [B*H][64][S] ----------------
__global__ __launch_bounds__(256) void k_vtrans_b(const ushort16* __restrict__ v,
                                                  ushort16* __restrict__ vT) {
  __shared__ ushort16 T[64][68];
  int bh = blockIdx.y, b = bh >> 4, h = bh & 15;
  int s0 = blockIdx.x * 64;
  int tid = threadIdx.x;
#pragma unroll
  for (int p = 0; p < 16; ++p) {
    int idx = p * 256 + tid;
    int r = idx >> 6, d = idx & 63;
    T[r][d] = v[(size_t)(b * kS + s0 + r) * kD + h * kHD + d];
  }
  __syncthreads();
#pragma unroll
  for (int p = 0; p < 16; ++p) {
    int idx = p * 256 + tid;
    int d = idx >> 6, c = idx & 63;
    vT[((size_t)bh * kHD + d) * kS + s0 + c] = T[c][d];
  }
}

// ---------------- MFMA flash attention ----------------
__global__ __launch_bounds__(256) void k_attn_mfma(const ushort16* __restrict__ qb,
                                                   const ushort16* __restrict__ kb,
                                                   const ushort16* __restrict__ vT,
                                                   float* __restrict__ outp,
                                                   float ratio2) {
  __shared__ __align__(16) ushort16 Ks[2 * 128 * 32];   // [ksub(d)][key][32]
  __shared__ __align__(16) ushort16 Vs[4 * 64 * 32];    // [ssub][d][32]
  __shared__ __align__(16) ushort16 Ps[4 * 4 * 16 * 32];// [wave][ksub(s)][row16][32]
  int bh = blockIdx.y, b = bh >> 4, h = bh & 15;
  int q0 = blockIdx.x * 128;
  int tid = threadIdx.x, lane = tid & 63, wave = tid >> 6;
  int c16 = lane & 15, quad = lane >> 4;
  int wq = wave * 32;

  short8x a_q[2][2];
#pragma unroll
  for (int i = 0; i < 2; ++i)
#pragma unroll
    for (int kk = 0; kk < 2; ++kk)
      a_q[i][kk] = *(const short8x*)&qb[(size_t)(b * kS + q0 + wq + i * 16 + c16) * kD +
                                        h * kHD + kk * 32 + quad * 8];

  float m_i[2][4], l_i[2][4];
  floatx4 o[2][4];
#pragma unroll
  for (int i = 0; i < 2; ++i)
#pragma unroll
    for (int r = 0; r < 4; ++r) { m_i[i][r] = -INFINITY; l_i[i][r] = 0.f; }
#pragma unroll
  for (int i = 0; i < 2; ++i)
#pragma unroll
    for (int n = 0; n < 4; ++n) o[i][n] = (floatx4)0.f;

  const ushort16* kbase = kb + ((size_t)b * kS) * kD + h * kHD;
  const ushort16* vbase = vT + (size_t)bh * kHD * kS;

  for (int k0 = 0; k0 < kS; k0 += 128) {
#pragma unroll
    for (int t = 0; t < 2; ++t)
#pragma unroll
      for (int cb = 0; cb < 2; ++cb) {
        int e = cb * 2048 + tid * 8;
        async16(kbase + (size_t)(k0 + (e >> 5)) * kD + t * 32 + (e & 31),
                Ks + t * 4096 + e);
      }
#pragma unroll
    for (int t = 0; t < 4; ++t) {
      int e = tid * 8;
      async16(vbase + (size_t)(e >> 5) * kS + k0 + t * 32 + (e & 31),
              Vs + t * 2048 + e);
    }
    __syncthreads();

#pragma unroll
    for (int i = 0; i < 2; ++i) {
      floatx4 s[8];
#pragma unroll
      for (int n = 0; n < 8; ++n) s[n] = (floatx4)0.f;
#pragma unroll
      for (int kkd = 0; kkd < 2; ++kkd)
#pragma unroll
        for (int n = 0; n < 8; ++n) {
          short8x bk = *(const short8x*)&Ks[kkd * 4096 + (n * 16 + c16) * 32 + quad * 8];
          s[n] = __builtin_amdgcn_mfma_f32_16x16x32_bf16(a_q[i][kkd], bk, s[n], 0, 0, 0);
        }

#pragma unroll
      for (int r = 0; r < 4; ++r) {
        float mx = s[0][r];
#pragma unroll
        for (int n = 1; n < 8; ++n) mx = fmaxf(mx, s[n][r]);
        mx = redMax16(mx);
        float mold = m_i[i][r];
        float mnew = fmaxf(mold, mx);
        float alpha = __expf(mold - mnew);
        m_i[i][r] = mnew;
        float rs = 0.f;
#pragma unroll
        for (int n = 0; n < 8; ++n) {
          float pp = __expf(s[n][r] - mnew);
          ushort16 pbv = f2b(pp);
          rs += b2f(pbv);
          Ps[(wave * 4 + (n >> 1)) * 512 + (quad * 4 + r) * 32 + (n & 1) * 16 + c16] = pbv;
        }
        rs = redSum16(rs);
        l_i[i][r] = l_i[i][r] * alpha + rs;
#pragma unroll
        for (int n = 0; n < 4; ++n) o[i][n][r] *= alpha;
      }

#pragma unroll
      for (int kk = 0; kk < 4; ++kk) {
        short8x ap = *(const short8x*)&Ps[(wave * 4 + kk) * 512 + c16 * 32 + quad * 8];
#pragma unroll
        for (int n = 0; n < 4; ++n) {
          short8x bv = *(const short8x*)&Vs[kk * 2048 + (n * 16 + c16) * 32 + quad * 8];
          o[i][n] = __builtin_amdgcn_mfma_f32_16x16x32_bf16(ap, bv, o[i][n], 0, 0, 0);
        }
      }
    }
    __syncthreads();
  }

#pragma unroll
  for (int i = 0; i < 2; ++i)
#pragma unroll
    for (int r = 0; r < 4; ++r) {
      float invl = 1.0f / l_i[i][r];
      float w[4];
      float pssq = 0.f;
#pragma unroll
      for (int n = 0; n < 4; ++n) { w[n] = o[i][n][r] * invl; pssq += w[n] * w[n]; }
      float ssq = redSum16(pssq);
      float coef = roundtrip_scale(sqrtf(ssq)) * ratio2;
      int row = b * kS + q0 + wq + i * 16 + quad * 4 + r;
#pragma unroll
      for (int n = 0; n < 4; ++n)
        outp[(size_t)row * kD + h * kHD + n * 16 + c16] = coef * w[n];
    }
}

// ---------------- roundtrip scale, fp32 in -> bf16 out ----------------
template <int WIDTH>
__global__ __launch_bounds__(256) void k_rt_scale_f2b(const float* __restrict__ p,
                                                      ushort16* __restrict__ out) {
  __shared__ float sred[4];
  constexpr int PER = WIDTH / 256;
  size_t base = (size_t)blockIdx.x * WIDTH;
  float v[PER];
  float ss = 0.f;
#pragma unroll
  for (int i = 0; i < PER; ++i) {
    v[i] = p[base + i * 256 + threadIdx.x];
    ss += v[i] * v[i];
  }
  ss = blockReduceSum256(ss, sred);
  float s = roundtrip_scale(sqrtf(ss));
#pragma unroll
  for (int i = 0; i < PER; ++i) out[base + i * 256 + threadIdx.x] = f2b(s * v[i]);
}

// ---------------- roundtrip scale, bf16 in/out (in place) ----------------
template <int WIDTH>
__global__ __launch_bounds__(256) void k_rt_scale_b2b(ushort16* __restrict__ p) {
  __shared__ float sred[4];
  constexpr int PER = WIDTH / 256;
  size_t base = (size_t)blockIdx.x * WIDTH;
  float v[PER];
  float ss = 0.f;
#pragma unroll
  for (int i = 0; i < PER; ++i) {
    v[i] = b2f(p[base + i * 256 + threadIdx.x]);
    ss += v[i] * v[i];
  }
  ss = blockReduceSum256(ss, sred);
  float s = roundtrip_scale(sqrtf(ss));
#pragma unroll
  for (int i = 0; i < PER; ++i) p[base + i * 256 + threadIdx.x] = f2b(s * v[i]);
}

// ---------------- mobius epilogue; ot = ot0 + ot1 (split-K partials) ----------------
__global__ __launch_bounds__(256) void k_epilogue2(const float* __restrict__ xres,
                                                   const float* __restrict__ ot0,
                                                   const float* __restrict__ ot1,
                                                   const float* __restrict__ ada,
                                                   int g_off,
                                                   float* __restrict__ out) {
  __shared__ float sred[4];
  int tok = blockIdx.x;
  int b = tok >> 10;
  size_t base = (size_t)tok * kD;
  float xv[4], tv[4];
  float ss = 0.f;
#pragma unroll
  for (int i = 0; i < 4; ++i) {
    int d = i * 256 + threadIdx.x;
    tv[i] = ot0[base + d] + ot1[base + d];
    xv[i] = xres[base + d];
    ss += tv[i] * tv[i];
  }
  ss = blockReduceSum256(ss, sred);
  float s5 = roundtrip_scale(sqrtf(ss));
  const float* gp = ada + b * 6 * kD + g_off;
  float at2 = 0.f;
#pragma unroll
  for (int i = 0; i < 4; ++i) {
    float a = gp[i * 256 + threadIdx.x] * s5 * tv[i];
    tv[i] = a;
    at2 += a * a;
  }
  at2 = blockReduceSum256(at2, sred);
  float nyraw = sqrtf(at2);
  float sy = expmap0_scale(nyraw);
  float ynorm = sy * nyraw;
  float y2 = ynorm * ynorm;
  float x2p = 0.f, xyp = 0.f;
#pragma unroll
  for (int i = 0; i < 4; ++i) {
    float y = sy * tv[i];
    tv[i] = y;
    x2p += xv[i] * xv[i];
    xyp += xv[i] * y;
  }
  float x2 = blockReduceSum256(x2p, sred);
  float xy = blockReduceSum256(xyp, sred);
  float cx = 1.0f + 2.0f * xy + y2;
  float cy = 1.0f - x2;
  float den = fmaxf(1.0f + 2.0f * xy + x2 * y2, EPSF);
  float invden = 1.0f / den;
#pragma unroll
  for (int i = 0; i < 4; ++i)
    out[base + i * 256 + threadIdx.x] = (cx * xv[i] + cy * tv[i]) * invden;
}

// ---------------------------------------------------------------------------
extern "C" void kernel_launch(void* const* d_in, const int* in_sizes, int n_in,
                              void* d_out, int out_size, void* d_ws, size_t ws_size,
                              hipStream_t stream) {
  const float* x     = (const float*)d_in[0];
  const float* t_emb = (const float*)d_in[1];
  const float* w_q = (const float*)d_in[2];  const float* b_q = (const float*)d_in[3];
  const float* w_k = (const float*)d_in[4];  const float* b_k = (const float*)d_in[5];
  const float* w_v = (const float*)d_in[6];  const float* b_v = (const float*)d_in[7];
  const float* w_o = (const float*)d_in[8];  const float* b_o = (const float*)d_in[9];
  const float* w_f1 = (const float*)d_in[10]; const float* b_f1 = (const float*)d_in[11];
  const float* w_f2 = (const float*)d_in[12]; const float* b_f2 = (const float*)d_in[13];
  const float* w_ada = (const float*)d_in[14]; const float* b_ada = (const float*)d_in[15];
  float* out = (float*)d_out;

  constexpr size_t ND = (size_t)kN * kD;    // 4 M
  constexpr size_t NF = (size_t)kN * kFF;   // 16 M
  constexpr size_t DD = (size_t)kD * kD;    // 1 M

  float* ws   = (float*)d_ws;
  float* ada  = ws;                 // 24576 f32
  float* qt   = ada + 6 * kD * kB;  // ND f32 (split-K partial 0)
  float* kt   = qt + ND;            // ND f32 (attn out; f2 partial 1)
  float* vt   = kt + ND;            // ND f32 (o partial 1 -> x_mid in place)
  ushort16* qbA = (ushort16*)(vt + ND);   // ND bf16 (lx / qb / rt(ao) / lx2)
  ushort16* kb  = qbA + ND;               // ND bf16 (q raw -> vT)
  ushort16* vTb = kb + ND;                // ND bf16 (k raw -> k scaled)
  ushort16* actB = vTb + ND;              // NF bf16 (v raw/scaled; h1)
  ushort16* wqT  = actB + NF;             // DD bf16 each
  ushort16* wkT  = wqT + DD;
  ushort16* wvT  = wkT + DD;
  ushort16* woT  = wvT + DD;
  ushort16* wf1T = woT + DD;              // FF*D
  ushort16* wf2T = wf1T + (size_t)kD * kFF;

  double bn = exp(lgamma(512.0) + lgamma(0.5) - lgamma(512.5));
  double bh = exp(lgamma(32.0) + lgamma(0.5) - lgamma(32.5));
  float R1 = (float)(bh / bn);
  float R2 = (float)(bn / bh);

  // 0) weight transpose + cast to bf16 [N][K]
  k_transpose_bf16<<<dim3(16, 16), 256, 0, stream>>>(w_q, wqT, kD, kD);
  k_transpose_bf16<<<dim3(16, 16), 256, 0, stream>>>(w_k, wkT, kD, kD);
  k_transpose_bf16<<<dim3(16, 16), 256, 0, stream>>>(w_v, wvT, kD, kD);
  k_transpose_bf16<<<dim3(16, 16), 256, 0, stream>>>(w_o, woT, kD, kD);
  k_transpose_bf16<<<dim3(64, 16), 256, 0, stream>>>(w_f1, wf1T, kD, kFF);
  k_transpose_bf16<<<dim3(16, 64), 256, 0, stream>>>(w_f2, wf2T, kFF, kD);
  // 1) ada
  k_ada<<<dim3(6 * kD / 256, kB), 256, 0, stream>>>(t_emb, w_ada, b_ada, ada);
  // 2) prenorm (msa): lx -> qbA (bf16)
  k_prenorm<<<kN, 256, 0, stream>>>(x, ada, 0 * kD, 1 * kD, qbA);
  // 3) q,k,v projections, bf16 out: q->kb, k->vTb, v->actB
  //    grid swapped: (rows=32, cols=8, 3) -> XCD = row%8, A L2-resident
  k_gemm_bf16<1, 1><<<dim3(kN / 128, kD / 128, 3), 256, 0, stream>>>(
      qbA, wqT, wkT, wvT, b_q, b_k, b_v, kb, vTb, actB, kN, kD, kD);
  // 4) head split (bf16): qb->qbA (pre-scaled 1/8), k scaled in vTb, v scaled in actB
  k_headsplit_b<<<kN, 256, 0, stream>>>(kb, vTb, actB, qbA, R1);
  // 5) V transpose: actB -> kb ([B*H][64][S] bf16)
  k_vtrans_b<<<dim3(kS / 64, kB * kH), 256, 0, stream>>>(actB, kb);
  // 6) MFMA flash attention -> kt (f32 tangent, per-head scaled)
  k_attn_mfma<<<dim3(kS / 128, kB * kH), 256, 0, stream>>>(qbA, vTb, kb, kt, R2);
  // 7) full-dim roundtrip -> qbA (bf16)
  k_rt_scale_f2b<kD><<<kN, 256, 0, stream>>>(kt, qbA);
  // 8) o projection, split-K=2 -> partials qt (z=0, +bias) and vt (z=1); swapped grid
  k_gemm_bf16<0, 2><<<dim3(kN / 128, kD / 128, 2), 256, 0, stream>>>(
      qbA, woT, woT, woT, b_o, b_o, b_o, qt, vt, vt, kN, kD, kD);
  // 9) mobius epilogue (msa): x_mid = mobius(x, qt+vt) -> vt (in-place safe)
  k_epilogue2<<<kN, 256, 0, stream>>>(x, qt, vt, ada, 2 * kD, vt);
  // 10) prenorm (mlp): lx2 -> qbA (bf16)
  k_prenorm<<<kN, 256, 0, stream>>>(vt, ada, 3 * kD, 4 * kD, qbA);
  // 11) f1 -> actB (bf16 direct); swapped grid (32, 32)
  k_gemm_bf16<1, 1><<<dim3(kN / 128, kFF / 128, 1), 256, 0, stream>>>(
      qbA, wf1T, wf1T, wf1T, b_f1, b_f1, b_f1, actB, actB, actB, kN, kFF, kD);
  // 12) roundtrip on h1 (bf16 in place)
  k_rt_scale_b2b<kFF><<<kN, 256, 0, stream>>>(actB);
  // 13) f2, split-K=2 -> partials qt (z=0, +bias) and kt (z=1); swapped grid
  k_gemm_bf16<0, 2><<<dim3(kN / 128, kD / 128, 2), 256, 0, stream>>>(
      actB, wf2T, wf2T, wf2T, b_f2, b_f2, b_f2, qt, kt, kt, kN, kD, kFF);
  // 14) mobius epilogue (mlp): out = mobius(vt, qt+kt)
  k_epilogue2<<<kN, 256, 0, stream>>>(vt, qt, kt, ada, 5 * kD, out);

  (void)in_sizes; (void)n_in; (void)out_size; (void)ws_size;
}

// Round 7
// 525.872 us; speedup vs baseline: 1.0642x; 1.0227x over previous
//
#include <hip/hip_runtime.h>
#include <cmath>

// ---------------------------------------------------------------------------
// Poincare transformer layer. Round 7: attention softmax stripped — scores
// provably bounded (|s|<=atanh(1-1e-5)^2/8 ~ 4.65) so no online max/rescale;
// l via ones-MFMA (no cross-lane shuffles in main loop); packed b32 P-writes
// with permuted-k LDS layout (permutation baked into V-transpose); Ps rows
// padded to 80 B (2-way banks = free). GEMMs unchanged from round 6.
// ---------------------------------------------------------------------------

constexpr int kD  = 1024;
constexpr int kH  = 16;
constexpr int kHD = 64;
constexpr int kFF = 4096;
constexpr int kB  = 4;
constexpr int kS  = 1024;
constexpr int kN  = kB * kS;   // 4096 tokens

#define EPSF 1e-7f
#define MTAF (1.0f - 1e-5f)
#define LOG2E 1.4426950408889634f

typedef unsigned int uint32;
typedef unsigned short ushort16;
typedef __attribute__((ext_vector_type(8))) short short8x;
typedef __attribute__((ext_vector_type(4))) float floatx4;

// ---------------- bf16 helpers ----------------
__device__ __forceinline__ ushort16 f2b(float f) {
  union { float f; uint32 u; } x; x.f = f;
  uint32 r = x.u + 0x7fffu + ((x.u >> 16) & 1u);   // RNE
  return (ushort16)(r >> 16);
}
__device__ __forceinline__ float b2f(ushort16 u) {
  union { uint32 u; float f; } x; x.u = ((uint32)u) << 16;
  return x.f;
}

// ---------------- math helpers ----------------
__device__ __forceinline__ float atanh_clipped(float n) {
  float c = fminf(n, MTAF);
  return 0.5f * logf((1.0f + c) / (1.0f - c));
}
__device__ __forceinline__ float logmap0_scale(float nraw) {
  float n = fmaxf(nraw, EPSF);
  return atanh_clipped(n) / n;
}
__device__ __forceinline__ float expmap0_scale(float nraw) {
  float n = fmaxf(nraw, EPSF);
  return tanhf(n) / n;
}
__device__ __forceinline__ float roundtrip_scale(float nraw) {
  float nu = fmaxf(nraw, EPSF);
  float se = tanhf(nu) / nu;
  float nb = fmaxf(se * nraw, EPSF);
  float sl = atanh_clipped(nb) / nb;
  return sl * se;
}

// ---------------- reductions ----------------
__device__ __forceinline__ float blockReduceSum256(float v, float* s4) {
#pragma unroll
  for (int o = 32; o > 0; o >>= 1) v += __shfl_xor(v, o);
  int wave = threadIdx.x >> 6;
  if ((threadIdx.x & 63) == 0) s4[wave] = v;
  __syncthreads();
  float r = s4[0] + s4[1] + s4[2] + s4[3];
  __syncthreads();
  return r;
}
__device__ __forceinline__ float waveReduceSum64(float v) {
#pragma unroll
  for (int o = 32; o > 0; o >>= 1) v += __shfl_xor(v, o);
  return v;
}
__device__ __forceinline__ float redSum16(float v) {
#pragma unroll
  for (int o = 8; o > 0; o >>= 1) v += __shfl_xor(v, o);
  return v;
}

// ---------------- async global->LDS, 16 bytes/lane ----------------
__device__ __forceinline__ void async16(const void* g, void* l) {
  __builtin_amdgcn_global_load_lds(
      (const __attribute__((address_space(1))) uint32*)g,
      (__attribute__((address_space(3))) uint32*)l, 16, 0, 0);
}

// ---------------- weight transpose + cast: src [K][N] f32 -> dst [N][K] bf16 ----
__global__ __launch_bounds__(256) void k_transpose_bf16(const float* __restrict__ src,
                                                        ushort16* __restrict__ dst,
                                                        int K, int N) {
  __shared__ float T[64][65];
  int n0 = blockIdx.x * 64, k0 = blockIdx.y * 64;
#pragma unroll
  for (int p = 0; p < 16; ++p) {
    int idx = p * 256 + threadIdx.x;
    int r = idx >> 6, c = idx & 63;
    T[r][c] = src[(size_t)(k0 + r) * N + n0 + c];
  }
  __syncthreads();
#pragma unroll
  for (int p = 0; p < 16; ++p) {
    int idx = p * 256 + threadIdx.x;
    int r = idx >> 6, c = idx & 63;   // r: n-local, c: k-local
    dst[(size_t)(n0 + r) * K + k0 + c] = f2b(T[c][r]);
  }
}

// ---------------- ada = t_emb @ w_ada + b_ada ----------------
__global__ __launch_bounds__(256) void k_ada(const float* __restrict__ t_emb,
                                             const float* __restrict__ w_ada,
                                             const float* __restrict__ b_ada,
                                             float* __restrict__ ada) {
  __shared__ float te[kD];
  int b = blockIdx.y;
  for (int i = threadIdx.x; i < kD; i += 256) te[i] = t_emb[b * kD + i];
  __syncthreads();
  int col = blockIdx.x * 256 + threadIdx.x;
  float acc = b_ada[col];
  for (int k = 0; k < kD; ++k) acc += te[k] * w_ada[(size_t)k * (6 * kD) + col];
  ada[b * 6 * kD + col] = acc;
}

// ---------------- prenorm -> bf16 GEMM input ----------------
__global__ __launch_bounds__(256) void k_prenorm(const float* __restrict__ x,
                                                 const float* __restrict__ ada,
                                                 int sh_off, int sc_off,
                                                 ushort16* __restrict__ out) {
  __shared__ float sred[4];
  int tok = blockIdx.x;
  int b = tok >> 10;
  const float* xp = x + (size_t)tok * kD;
  float xv[4];
  float ss = 0.f;
#pragma unroll
  for (int i = 0; i < 4; ++i) {
    xv[i] = xp[i * 256 + threadIdx.x];
    ss += xv[i] * xv[i];
  }
  ss = blockReduceSum256(ss, sred);
  float sl = logmap0_scale(sqrtf(ss));
  float sum = 0.f;
#pragma unroll
  for (int i = 0; i < 4; ++i) { xv[i] *= sl; sum += xv[i]; }
  sum = blockReduceSum256(sum, sred);
  float mean = sum * (1.0f / kD);
  float vs = 0.f;
#pragma unroll
  for (int i = 0; i < 4; ++i) { xv[i] -= mean; vs += xv[i] * xv[i]; }
  vs = blockReduceSum256(vs, sred);
  float inv = rsqrtf(vs * (1.0f / kD) + 1e-6f);
  const float* shp = ada + b * 6 * kD + sh_off;
  const float* scp = ada + b * 6 * kD + sc_off;
  float uu = 0.f;
#pragma unroll
  for (int i = 0; i < 4; ++i) {
    int d = i * 256 + threadIdx.x;
    float u = xv[i] * inv * (1.0f + scp[d]) + shp[d];
    xv[i] = u;
    uu += u * u;
  }
  uu = blockReduceSum256(uu, sred);
  float s = roundtrip_scale(sqrtf(uu));
  ushort16* op = out + (size_t)tok * kD;
#pragma unroll
  for (int i = 0; i < 4; ++i) op[i * 256 + threadIdx.x] = f2b(s * xv[i]);
}

// ---------------- bf16 MFMA GEMM: C = A @ Bt^T + bias ----------------
// GRID: (M/128, N/128, Z)  -- row tiles on blockIdx.x so XCD = row%8.
template <int OUT_BF16, int KSPLIT>
__global__ __launch_bounds__(256) void k_gemm_bf16(
    const ushort16* __restrict__ A,
    const ushort16* __restrict__ Bt0, const ushort16* __restrict__ Bt1,
    const ushort16* __restrict__ Bt2,
    const float* __restrict__ bias0, const float* __restrict__ bias1,
    const float* __restrict__ bias2,
    void* __restrict__ C0, void* __restrict__ C1, void* __restrict__ C2,
    int M, int N, int K) {
  const ushort16* Bt;
  const float* bias;
  void* C;
  int k_lo, k_hi;
  bool add_bias;
  if (KSPLIT == 1) {
    Bt = (blockIdx.z == 0) ? Bt0 : ((blockIdx.z == 1) ? Bt1 : Bt2);
    bias = (blockIdx.z == 0) ? bias0 : ((blockIdx.z == 1) ? bias1 : bias2);
    C = (blockIdx.z == 0) ? C0 : ((blockIdx.z == 1) ? C1 : C2);
    k_lo = 0; k_hi = K; add_bias = true;
  } else {
    Bt = Bt0; bias = bias0;
    C = (blockIdx.z == 0) ? C0 : C1;
    int kchunk = K / KSPLIT;
    k_lo = blockIdx.z * kchunk; k_hi = k_lo + kchunk;
    add_bias = (blockIdx.z == 0);
  }

  __shared__ __align__(16) ushort16 As[128 * 32];
  __shared__ __align__(16) ushort16 Bs[128 * 32];

  int tid = threadIdx.x;
  int lane = tid & 63;
  int wave = tid >> 6;
  int wm = (wave >> 1) * 64, wn = (wave & 1) * 64;
  int row0 = blockIdx.x * 128, col0 = blockIdx.y * 128;   // swapped grid

  int e0 = tid * 8;
  int ar0 = e0 >> 5, ac0 = e0 & 31;
  int e1 = e0 + 2048;
  int ar1 = e1 >> 5, ac1 = e1 & 31;
  const ushort16* Ag = A + (size_t)row0 * K;
  const ushort16* Bg = Bt + (size_t)col0 * K;

  floatx4 acc[4][4];
#pragma unroll
  for (int i = 0; i < 4; ++i)
#pragma unroll
    for (int j = 0; j < 4; ++j) acc[i][j] = (floatx4)0.f;

  for (int k0 = k_lo; k0 < k_hi; k0 += 32) {
    async16(Ag + (size_t)ar0 * K + k0 + ac0, As + e0);
    async16(Ag + (size_t)ar1 * K + k0 + ac1, As + e1);
    async16(Bg + (size_t)ar0 * K + k0 + ac0, Bs + e0);
    async16(Bg + (size_t)ar1 * K + k0 + ac1, Bs + e1);
    __syncthreads();

    short8x a[4], b[4];
#pragma unroll
    for (int i = 0; i < 4; ++i) {
      a[i] = *(const short8x*)&As[(wm + i * 16 + (lane & 15)) * 32 + (lane >> 4) * 8];
      b[i] = *(const short8x*)&Bs[(wn + i * 16 + (lane & 15)) * 32 + (lane >> 4) * 8];
    }
#pragma unroll
    for (int i = 0; i < 4; ++i)
#pragma unroll
      for (int j = 0; j < 4; ++j)
        acc[i][j] = __builtin_amdgcn_mfma_f32_16x16x32_bf16(a[i], b[j], acc[i][j], 0, 0, 0);
    __syncthreads();
  }

  float bv[4];
#pragma unroll
  for (int j = 0; j < 4; ++j)
    bv[j] = add_bias ? bias[col0 + wn + j * 16 + (lane & 15)] : 0.f;
  int rowq = (lane >> 4) * 4;
#pragma unroll
  for (int i = 0; i < 4; ++i) {
    int rbase = row0 + wm + i * 16 + rowq;
#pragma unroll
    for (int j = 0; j < 4; ++j) {
      int c = col0 + wn + j * 16 + (lane & 15);
#pragma unroll
      for (int r = 0; r < 4; ++r) {
        float v = acc[i][j][r] + bv[j];
        if (OUT_BF16)
          ((ushort16*)C)[(size_t)(rbase + r) * N + c] = f2b(v);
        else
          ((float*)C)[(size_t)(rbase + r) * N + c] = v;
      }
    }
  }
}

// ---------------- head split, all-bf16: q->qb_out (pre-scaled 0.125*log2e),
// k,v scaled IN PLACE. Folds _to_heads + logmap0 scales. ----------------
__global__ __launch_bounds__(256) void k_headsplit_b(const ushort16* __restrict__ q_in,
                                                     ushort16* __restrict__ k_io,
                                                     ushort16* __restrict__ v_io,
                                                     ushort16* __restrict__ qb_out,
                                                     float ratio) {
  __shared__ float sh[16];
  int tok = blockIdx.x;
  int tid = threadIdx.x, wave = tid >> 6;
#pragma unroll
  for (int t = 0; t < 3; ++t) {
    const ushort16* p = (t == 0 ? q_in : (t == 1 ? (const ushort16*)k_io
                                                 : (const ushort16*)v_io)) +
                        (size_t)tok * kD;
    float val[4], hs[4];
#pragma unroll
    for (int i = 0; i < 4; ++i) {
      val[i] = b2f(p[i * 256 + tid]);
      hs[i] = waveReduceSum64(val[i] * val[i]);  // head (i*4 + wave) sumsq
    }
    if ((tid & 63) == 0) {
#pragma unroll
      for (int i = 0; i < 4; ++i) sh[i * 4 + wave] = hs[i];
    }
    __syncthreads();
    float tot = 0.f;
#pragma unroll
    for (int j = 0; j < 16; ++j) tot += sh[j];
    float s1 = roundtrip_scale(sqrtf(tot));
    float c = s1 * ratio;
    ushort16* op = (t == 0 ? qb_out : (t == 1 ? k_io : v_io)) + (size_t)tok * kD;
#pragma unroll
    for (int i = 0; i < 4; ++i) {
      float m = c * sqrtf(hs[i]);
      float s2 = roundtrip_scale(m);
      float ov = c * s2 * val[i];
      // q: fold 1/sqrt(HD) * log2(e) so attention can use exp2 directly
      op[i * 256 + tid] = f2b(t == 0 ? (0.125f * LOG2E) * ov : ov);
    }
    __syncthreads();
  }
}

// ---------------- V transpose: v bf16 [N][D] -> vT bf16 [B*H][64][S],
// with k-permutation pi(s)= (s&15)*2 + (s>>4) within each 32-block (matches
// the packed P-write layout in attention). ----------------
__global__ __launch_bounds__(256) void k_vtrans_b(const ushort16* __restrict__ v,
                                                  ushort16* __restrict__ vT) {
  __shared__ ushort16 T[64][68];
  int bh = blockIdx.y, b = bh >> 4, h = bh & 15;
  int s0 = blockIdx.x * 64;
  int tid = threadIdx.x;
#pragma unroll
  for (int p = 0; p < 16; ++p) {
    int idx = p * 256 + tid;
    int r = idx >> 6, d = idx & 63;
    T[r][d] = v[(size_t)(b * kS + s0 + r) * kD + h * kHD + d];
  }
  __syncthreads();
#pragma unroll
  for (int p = 0; p < 16; ++p) {
    int idx = p * 256 + tid;
    int d = idx >> 6, c = idx & 63;
    int cp = (c & 32) | ((c & 15) << 1) | ((c >> 4) & 1);  // permuted within 32-block
    vT[((size_t)bh * kHD + d) * kS + s0 + cp] = T[c][d];
  }
}

// ---------------- MFMA flash attention, max-free softmax ----------------
// Scores bounded: |qt_h|,|kt_h| <= atanh(1-1e-5)=6.103 -> |s|<=4.65 (pre-log2e).
// p = exp2(s') directly; l = P @ ones via MFMA. No cross-lane shuffles in loop.
__global__ __launch_bounds__(256) void k_attn_mfma(const ushort16* __restrict__ qb,
                                                   const ushort16* __restrict__ kb,
                                                   const ushort16* __restrict__ vT,
                                                   float* __restrict__ outp,
                                                   float ratio2) {
  __shared__ __align__(16) ushort16 Ks[2 * 128 * 32];      // [dsub][key][32]
  __shared__ __align__(16) ushort16 Vs[4 * 64 * 32];       // [ssub][d][32] (permuted k)
  __shared__ __align__(16) ushort16 Ps[4 * 4 * 16 * 40];   // [wave][kk][row16][40pad]
  int bh = blockIdx.y, b = bh >> 4, h = bh & 15;
  int q0 = blockIdx.x * 128;
  int tid = threadIdx.x, lane = tid & 63, wave = tid >> 6;
  int c16 = lane & 15, quad = lane >> 4;
  int wq = wave * 32;

  short8x a_q[2][2];
#pragma unroll
  for (int i = 0; i < 2; ++i)
#pragma unroll
    for (int kk = 0; kk < 2; ++kk)
      a_q[i][kk] = *(const short8x*)&qb[(size_t)(b * kS + q0 + wq + i * 16 + c16) * kD +
                                        h * kHD + kk * 32 + quad * 8];

  short8x ones;
#pragma unroll
  for (int j = 0; j < 8; ++j) ones[j] = (short)0x3F80;  // bf16 1.0

  floatx4 o[2][4], ol[2];
#pragma unroll
  for (int i = 0; i < 2; ++i) {
    ol[i] = (floatx4)0.f;
#pragma unroll
    for (int n = 0; n < 4; ++n) o[i][n] = (floatx4)0.f;
  }

  const ushort16* kbase = kb + ((size_t)b * kS) * kD + h * kHD;
  const ushort16* vbase = vT + (size_t)bh * kHD * kS;

  for (int k0 = 0; k0 < kS; k0 += 128) {
#pragma unroll
    for (int t = 0; t < 2; ++t)
#pragma unroll
      for (int cb = 0; cb < 2; ++cb) {
        int e = cb * 2048 + tid * 8;
        async16(kbase + (size_t)(k0 + (e >> 5)) * kD + t * 32 + (e & 31),
                Ks + t * 4096 + e);
      }
#pragma unroll
    for (int t = 0; t < 4; ++t) {
      int e = tid * 8;
      async16(vbase + (size_t)(e >> 5) * kS + k0 + t * 32 + (e & 31),
              Vs + t * 2048 + e);
    }
    __syncthreads();

#pragma unroll
    for (int i = 0; i < 2; ++i) {
      floatx4 s[8];
#pragma unroll
      for (int n = 0; n < 8; ++n) s[n] = (floatx4)0.f;
#pragma unroll
      for (int kkd = 0; kkd < 2; ++kkd)
#pragma unroll
        for (int n = 0; n < 8; ++n) {
          short8x bk = *(const short8x*)&Ks[kkd * 4096 + (n * 16 + c16) * 32 + quad * 8];
          s[n] = __builtin_amdgcn_mfma_f32_16x16x32_bf16(a_q[i][kkd], bk, s[n], 0, 0, 0);
        }

      // p = exp2(s) (log2e pre-folded into q); packed b32 writes, permuted k
#pragma unroll
      for (int r = 0; r < 4; ++r) {
#pragma unroll
        for (int j = 0; j < 4; ++j) {
          uint32 u0 = (uint32)f2b(exp2f(s[2 * j][r]));
          uint32 u1 = (uint32)f2b(exp2f(s[2 * j + 1][r]));
          *(uint32*)&Ps[(((wave * 4 + j) * 16) + (quad * 4 + r)) * 40 + c16 * 2] =
              u0 | (u1 << 16);
        }
      }

      // o += P @ V ; l += P @ ones
#pragma unroll
      for (int kk = 0; kk < 4; ++kk) {
        short8x ap = *(const short8x*)&Ps[(((wave * 4 + kk) * 16) + c16) * 40 + quad * 8];
#pragma unroll
        for (int n = 0; n < 4; ++n) {
          short8x bv = *(const short8x*)&Vs[kk * 2048 + (n * 16 + c16) * 32 + quad * 8];
          o[i][n] = __builtin_amdgcn_mfma_f32_16x16x32_bf16(ap, bv, o[i][n], 0, 0, 0);
        }
        ol[i] = __builtin_amdgcn_mfma_f32_16x16x32_bf16(ap, ones, ol[i], 0, 0, 0);
      }
    }
    __syncthreads();
  }

#pragma unroll
  for (int i = 0; i < 2; ++i)
#pragma unroll
    for (int r = 0; r < 4; ++r) {
      float invl = 1.0f / ol[i][r];
      float w[4];
      float pssq = 0.f;
#pragma unroll
      for (int n = 0; n < 4; ++n) { w[n] = o[i][n][r] * invl; pssq += w[n] * w[n]; }
      float ssq = redSum16(pssq);
      float coef = roundtrip_scale(sqrtf(ssq)) * ratio2;
      int row = b * kS + q0 + wq + i * 16 + quad * 4 + r;
#pragma unroll
      for (int n = 0; n < 4; ++n)
        outp[(size_t)row * kD + h * kHD + n * 16 + c16] = coef * w[n];
    }
}

// ---------------- roundtrip scale, fp32 in -> bf16 out ----------------
template <int WIDTH>
__global__ __launch_bounds__(256) void k_rt_scale_f2b(const float* __restrict__ p,
                                                      ushort16* __restrict__ out) {
  __shared__ float sred[4];
  constexpr int PER = WIDTH / 256;
  size_t base = (size_t)blockIdx.x * WIDTH;
  float v[PER];
  float ss = 0.f;
#pragma unroll
  for (int i = 0; i < PER; ++i) {
    v[i] = p[base + i * 256 + threadIdx.x];
    ss += v[i] * v[i];
  }
  ss = blockReduceSum256(ss, sred);
  float s = roundtrip_scale(sqrtf(ss));
#pragma unroll
  for (int i = 0; i < PER; ++i) out[base + i * 256 + threadIdx.x] = f2b(s * v[i]);
}

// ---------------- roundtrip scale, bf16 in/out (in place) ----------------
template <int WIDTH>
__global__ __launch_bounds__(256) void k_rt_scale_b2b(ushort16* __restrict__ p) {
  __shared__ float sred[4];
  constexpr int PER = WIDTH / 256;
  size_t base = (size_t)blockIdx.x * WIDTH;
  float v[PER];
  float ss = 0.f;
#pragma unroll
  for (int i = 0; i < PER; ++i) {
    v[i] = b2f(p[base + i * 256 + threadIdx.x]);
    ss += v[i] * v[i];
  }
  ss = blockReduceSum256(ss, sred);
  float s = roundtrip_scale(sqrtf(ss));
#pragma unroll
  for (int i = 0; i < PER; ++i) p[base + i * 256 + threadIdx.x] = f2b(s * v[i]);
}

// ---------------- mobius epilogue; ot = ot0 + ot1 (split-K partials) ----------------
__global__ __launch_bounds__(256) void k_epilogue2(const float* __restrict__ xres,
                                                   const float* __restrict__ ot0,
                                                   const float* __restrict__ ot1,
                                                   const float* __restrict__ ada,
                                                   int g_off,
                                                   float* __restrict__ out) {
  __shared__ float sred[4];
  int tok = blockIdx.x;
  int b = tok >> 10;
  size_t base = (size_t)tok * kD;
  float xv[4], tv[4];
  float ss = 0.f;
#pragma unroll
  for (int i = 0; i < 4; ++i) {
    int d = i * 256 + threadIdx.x;
    tv[i] = ot0[base + d] + ot1[base + d];
    xv[i] = xres[base + d];
    ss += tv[i] * tv[i];
  }
  ss = blockReduceSum256(ss, sred);
  float s5 = roundtrip_scale(sqrtf(ss));
  const float* gp = ada + b * 6 * kD + g_off;
  float at2 = 0.f;
#pragma unroll
  for (int i = 0; i < 4; ++i) {
    float a = gp[i * 256 + threadIdx.x] * s5 * tv[i];
    tv[i] = a;
    at2 += a * a;
  }
  at2 = blockReduceSum256(at2, sred);
  float nyraw = sqrtf(at2);
  float sy = expmap0_scale(nyraw);
  float ynorm = sy * nyraw;
  float y2 = ynorm * ynorm;
  float x2p = 0.f, xyp = 0.f;
#pragma unroll
  for (int i = 0; i < 4; ++i) {
    float y = sy * tv[i];
    tv[i] = y;
    x2p += xv[i] * xv[i];
    xyp += xv[i] * y;
  }
  float x2 = blockReduceSum256(x2p, sred);
  float xy = blockReduceSum256(xyp, sred);
  float cx = 1.0f + 2.0f * xy + y2;
  float cy = 1.0f - x2;
  float den = fmaxf(1.0f + 2.0f * xy + x2 * y2, EPSF);
  float invden = 1.0f / den;
#pragma unroll
  for (int i = 0; i < 4; ++i)
    out[base + i * 256 + threadIdx.x] = (cx * xv[i] + cy * tv[i]) * invden;
}

// ---------------------------------------------------------------------------
extern "C" void kernel_launch(void* const* d_in, const int* in_sizes, int n_in,
                              void* d_out, int out_size, void* d_ws, size_t ws_size,
                              hipStream_t stream) {
  const float* x     = (const float*)d_in[0];
  const float* t_emb = (const float*)d_in[1];
  const float* w_q = (const float*)d_in[2];  const float* b_q = (const float*)d_in[3];
  const float* w_k = (const float*)d_in[4];  const float* b_k = (const float*)d_in[5];
  const float* w_v = (const float*)d_in[6];  const float* b_v = (const float*)d_in[7];
  const float* w_o = (const float*)d_in[8];  const float* b_o = (const float*)d_in[9];
  const float* w_f1 = (const float*)d_in[10]; const float* b_f1 = (const float*)d_in[11];
  const float* w_f2 = (const float*)d_in[12]; const float* b_f2 = (const float*)d_in[13];
  const float* w_ada = (const float*)d_in[14]; const float* b_ada = (const float*)d_in[15];
  float* out = (float*)d_out;

  constexpr size_t ND = (size_t)kN * kD;    // 4 M
  constexpr size_t NF = (size_t)kN * kFF;   // 16 M
  constexpr size_t DD = (size_t)kD * kD;    // 1 M

  float* ws   = (float*)d_ws;
  float* ada  = ws;                 // 24576 f32
  float* qt   = ada + 6 * kD * kB;  // ND f32 (split-K partial 0)
  float* kt   = qt + ND;            // ND f32 (attn out; f2 partial 1)
  float* vt   = kt + ND;            // ND f32 (o partial 1 -> x_mid in place)
  ushort16* qbA = (ushort16*)(vt + ND);   // ND bf16 (lx / qb / rt(ao) / lx2)
  ushort16* kb  = qbA + ND;               // ND bf16 (q raw -> vT)
  ushort16* vTb = kb + ND;                // ND bf16 (k raw -> k scaled)
  ushort16* actB = vTb + ND;              // NF bf16 (v raw/scaled; h1)
  ushort16* wqT  = actB + NF;             // DD bf16 each
  ushort16* wkT  = wqT + DD;
  ushort16* wvT  = wkT + DD;
  ushort16* woT  = wvT + DD;
  ushort16* wf1T = woT + DD;              // FF*D
  ushort16* wf2T = wf1T + (size_t)kD * kFF;

  double bn = exp(lgamma(512.0) + lgamma(0.5) - lgamma(512.5));
  double bh = exp(lgamma(32.0) + lgamma(0.5) - lgamma(32.5));
  float R1 = (float)(bh / bn);
  float R2 = (float)(bn / bh);

  // 0) weight transpose + cast to bf16 [N][K]
  k_transpose_bf16<<<dim3(16, 16), 256, 0, stream>>>(w_q, wqT, kD, kD);
  k_transpose_bf16<<<dim3(16, 16), 256, 0, stream>>>(w_k, wkT, kD, kD);
  k_transpose_bf16<<<dim3(16, 16), 256, 0, stream>>>(w_v, wvT, kD, kD);
  k_transpose_bf16<<<dim3(16, 16), 256, 0, stream>>>(w_o, woT, kD, kD);
  k_transpose_bf16<<<dim3(64, 16), 256, 0, stream>>>(w_f1, wf1T, kD, kFF);
  k_transpose_bf16<<<dim3(16, 64), 256, 0, stream>>>(w_f2, wf2T, kFF, kD);
  // 1) ada
  k_ada<<<dim3(6 * kD / 256, kB), 256, 0, stream>>>(t_emb, w_ada, b_ada, ada);
  // 2) prenorm (msa): lx -> qbA (bf16)
  k_prenorm<<<kN, 256, 0, stream>>>(x, ada, 0 * kD, 1 * kD, qbA);
  // 3) q,k,v projections, bf16 out: q->kb, k->vTb, v->actB (swapped grid)
  k_gemm_bf16<1, 1><<<dim3(kN / 128, kD / 128, 3), 256, 0, stream>>>(
      qbA, wqT, wkT, wvT, b_q, b_k, b_v, kb, vTb, actB, kN, kD, kD);
  // 4) head split (bf16): qb->qbA (pre-scaled 0.125*log2e), k in vTb, v in actB
  k_headsplit_b<<<kN, 256, 0, stream>>>(kb, vTb, actB, qbA, R1);
  // 5) V transpose (k-permuted): actB -> kb ([B*H][64][S] bf16)
  k_vtrans_b<<<dim3(kS / 64, kB * kH), 256, 0, stream>>>(actB, kb);
  // 6) MFMA flash attention (max-free) -> kt (f32 tangent, per-head scaled)
  k_attn_mfma<<<dim3(kS / 128, kB * kH), 256, 0, stream>>>(qbA, vTb, kb, kt, R2);
  // 7) full-dim roundtrip -> qbA (bf16)
  k_rt_scale_f2b<kD><<<kN, 256, 0, stream>>>(kt, qbA);
  // 8) o projection, split-K=2 -> partials qt (z=0, +bias) and vt (z=1)
  k_gemm_bf16<0, 2><<<dim3(kN / 128, kD / 128, 2), 256, 0, stream>>>(
      qbA, woT, woT, woT, b_o, b_o, b_o, qt, vt, vt, kN, kD, kD);
  // 9) mobius epilogue (msa): x_mid = mobius(x, qt+vt) -> vt (in-place safe)
  k_epilogue2<<<kN, 256, 0, stream>>>(x, qt, vt, ada, 2 * kD, vt);
  // 10) prenorm (mlp): lx2 -> qbA (bf16)
  k_prenorm<<<kN, 256, 0, stream>>>(vt, ada, 3 * kD, 4 * kD, qbA);
  // 11) f1 -> actB (bf16 direct); swapped grid (32, 32)
  k_gemm_bf16<1, 1><<<dim3(kN / 128, kFF / 128, 1), 256, 0, stream>>>(
      qbA, wf1T, wf1T, wf1T, b_f1, b_f1, b_f1, actB, actB, actB, kN, kFF, kD);
  // 12) roundtrip on h1 (bf16 in place)
  k_rt_scale_b2b<kFF><<<kN, 256, 0, stream>>>(actB);
  // 13) f2, split-K=2 -> partials qt (z=0, +bias) and kt (z=1)
  k_gemm_bf16<0, 2><<<dim3(kN / 128, kD / 128, 2), 256, 0, stream>>>(
      actB, wf2T, wf2T, wf2T, b_f2, b_f2, b_f2, qt, kt, kt, kN, kD, kFF);
  // 14) mobius epilogue (mlp): out = mobius(vt, qt+kt)
  k_epilogue2<<<kN, 256, 0, stream>>>(vt, qt, kt, ada, 5 * kD, out);

  (void)in_sizes; (void)n_in; (void)out_size; (void)ws_size;
}

// Round 8
// 464.519 us; speedup vs baseline: 1.2047x; 1.1321x over previous
//
#include <hip/hip_runtime.h>
#include <cmath>

// ---------------------------------------------------------------------------
// Poincare transformer layer. Round 8: mid-field sweep — ada K-chunked (was
// 0.4 blocks/CU latency-bound), all elementwise kernels vectorized (float4 /
// b64 / b128), epilogue(msa)+prenorm(mlp) fused, attention grid swapped for
// K/V L2 residency (bh -> XCD), 4x DxD transposes merged into one launch.
// GEMMs and attention core unchanged from round 7.
// ---------------------------------------------------------------------------

constexpr int kD  = 1024;
constexpr int kH  = 16;
constexpr int kHD = 64;
constexpr int kFF = 4096;
constexpr int kB  = 4;
constexpr int kS  = 1024;
constexpr int kN  = kB * kS;   // 4096 tokens

#define EPSF 1e-7f
#define MTAF (1.0f - 1e-5f)
#define LOG2E 1.4426950408889634f

typedef unsigned int uint32;
typedef unsigned short ushort16;
typedef __attribute__((ext_vector_type(8))) short short8x;
typedef __attribute__((ext_vector_type(4))) float floatx4;

// ---------------- bf16 helpers ----------------
__device__ __forceinline__ ushort16 f2b(float f) {
  union { float f; uint32 u; } x; x.f = f;
  uint32 r = x.u + 0x7fffu + ((x.u >> 16) & 1u);   // RNE
  return (ushort16)(r >> 16);
}
__device__ __forceinline__ float b2f(ushort16 u) {
  union { uint32 u; float f; } x; x.u = ((uint32)u) << 16;
  return x.f;
}
// 4 consecutive bf16 <-> float[4] (8B vector ops)
__device__ __forceinline__ void load_b4(const ushort16* p, float v[4]) {
  uint2 u = *(const uint2*)p;
  v[0] = b2f((ushort16)(u.x & 0xffff)); v[1] = b2f((ushort16)(u.x >> 16));
  v[2] = b2f((ushort16)(u.y & 0xffff)); v[3] = b2f((ushort16)(u.y >> 16));
}
__device__ __forceinline__ void store_b4(ushort16* p, const float v[4]) {
  uint2 u;
  u.x = (uint32)f2b(v[0]) | ((uint32)f2b(v[1]) << 16);
  u.y = (uint32)f2b(v[2]) | ((uint32)f2b(v[3]) << 16);
  *(uint2*)p = u;
}

// ---------------- math helpers ----------------
__device__ __forceinline__ float atanh_clipped(float n) {
  float c = fminf(n, MTAF);
  return 0.5f * logf((1.0f + c) / (1.0f - c));
}
__device__ __forceinline__ float logmap0_scale(float nraw) {
  float n = fmaxf(nraw, EPSF);
  return atanh_clipped(n) / n;
}
__device__ __forceinline__ float expmap0_scale(float nraw) {
  float n = fmaxf(nraw, EPSF);
  return tanhf(n) / n;
}
__device__ __forceinline__ float roundtrip_scale(float nraw) {
  float nu = fmaxf(nraw, EPSF);
  float se = tanhf(nu) / nu;
  float nb = fmaxf(se * nraw, EPSF);
  float sl = atanh_clipped(nb) / nb;
  return sl * se;
}

// ---------------- reductions ----------------
__device__ __forceinline__ float blockReduceSum256(float v, float* s4) {
#pragma unroll
  for (int o = 32; o > 0; o >>= 1) v += __shfl_xor(v, o);
  int wave = threadIdx.x >> 6;
  if ((threadIdx.x & 63) == 0) s4[wave] = v;
  __syncthreads();
  float r = s4[0] + s4[1] + s4[2] + s4[3];
  __syncthreads();
  return r;
}
__device__ __forceinline__ float redSum16(float v) {
#pragma unroll
  for (int o = 8; o > 0; o >>= 1) v += __shfl_xor(v, o);
  return v;
}

// ---------------- async global->LDS, 16 bytes/lane ----------------
__device__ __forceinline__ void async16(const void* g, void* l) {
  __builtin_amdgcn_global_load_lds(
      (const __attribute__((address_space(1))) uint32*)g,
      (__attribute__((address_space(3))) uint32*)l, 16, 0, 0);
}

// ---------------- weight transpose + cast: src [K][N] f32 -> dst [N][K] bf16 ----
__device__ __forceinline__ void transpose_tile(const float* __restrict__ src,
                                               ushort16* __restrict__ dst,
                                               int K, int N, int n0, int k0) {
  __shared__ float T[64][65];
  int tid = threadIdx.x;
#pragma unroll
  for (int p = 0; p < 4; ++p) {
    int idx = p * 1024 + tid * 4;
    int r = idx >> 6, c = idx & 63;
    float4 t = *(const float4*)&src[(size_t)(k0 + r) * N + n0 + c];
    T[r][c] = t.x; T[r][c + 1] = t.y; T[r][c + 2] = t.z; T[r][c + 3] = t.w;
  }
  __syncthreads();
#pragma unroll
  for (int p = 0; p < 4; ++p) {
    int idx = p * 1024 + tid * 4;
    int r = idx >> 6, c = idx & 63;   // r: n-local, c: k-local (4 consecutive)
    float v[4] = {T[c][r], T[c + 1][r], T[c + 2][r], T[c + 3][r]};
    store_b4(&dst[(size_t)(n0 + r) * K + k0 + c], v);
  }
}
__global__ __launch_bounds__(256) void k_transpose_bf16(const float* __restrict__ src,
                                                        ushort16* __restrict__ dst,
                                                        int K, int N) {
  transpose_tile(src, dst, K, N, blockIdx.x * 64, blockIdx.y * 64);
}
// 4 DxD transposes in one launch (z selects)
__global__ __launch_bounds__(256) void k_transpose4(
    const float* __restrict__ s0, const float* __restrict__ s1,
    const float* __restrict__ s2, const float* __restrict__ s3,
    ushort16* __restrict__ d0, ushort16* __restrict__ d1,
    ushort16* __restrict__ d2, ushort16* __restrict__ d3) {
  const float* src = (blockIdx.z == 0) ? s0 : (blockIdx.z == 1) ? s1
                    : (blockIdx.z == 2) ? s2 : s3;
  ushort16* dst = (blockIdx.z == 0) ? d0 : (blockIdx.z == 1) ? d1
                 : (blockIdx.z == 2) ? d2 : d3;
  transpose_tile(src, dst, kD, kD, blockIdx.x * 64, blockIdx.y * 64);
}

// ---------------- ada = t_emb @ w_ada + b_ada (K-chunked GEMV) ----------------
// grid (6144/64, B). block: 64 cols x 4 K-chunks of 256 -> 4x shorter chain.
__global__ __launch_bounds__(256) void k_ada(const float* __restrict__ t_emb,
                                             const float* __restrict__ w_ada,
                                             const float* __restrict__ b_ada,
                                             float* __restrict__ ada) {
  __shared__ float te[kD];
  __shared__ float part[4][64];
  int b = blockIdx.y;
  int tid = threadIdx.x;
  {
    float4 t = *(const float4*)&t_emb[b * kD + tid * 4];
    te[tid * 4] = t.x; te[tid * 4 + 1] = t.y; te[tid * 4 + 2] = t.z; te[tid * 4 + 3] = t.w;
  }
  __syncthreads();
  int c = tid & 63, kc = tid >> 6;
  int col = blockIdx.x * 64 + c;
  float acc = 0.f;
#pragma unroll 8
  for (int k = kc * 256; k < kc * 256 + 256; ++k)
    acc += te[k] * w_ada[(size_t)k * (6 * kD) + col];
  part[kc][c] = acc;
  __syncthreads();
  if (tid < 64)
    ada[b * 6 * kD + blockIdx.x * 64 + tid] =
        part[0][tid] + part[1][tid] + part[2][tid] + part[3][tid] +
        b_ada[blockIdx.x * 64 + tid];
}

// ---------------- prenorm -> bf16 GEMM input (vectorized) ----------------
__global__ __launch_bounds__(256) void k_prenorm(const float* __restrict__ x,
                                                 const float* __restrict__ ada,
                                                 int sh_off, int sc_off,
                                                 ushort16* __restrict__ out) {
  __shared__ float sred[4];
  int tok = blockIdx.x;
  int b = tok >> 10;
  int d4 = threadIdx.x * 4;
  float xv[4];
  *(float4*)xv = *(const float4*)&x[(size_t)tok * kD + d4];
  float ss = xv[0] * xv[0] + xv[1] * xv[1] + xv[2] * xv[2] + xv[3] * xv[3];
  ss = blockReduceSum256(ss, sred);
  float sl = logmap0_scale(sqrtf(ss));
  float sum = 0.f;
#pragma unroll
  for (int i = 0; i < 4; ++i) { xv[i] *= sl; sum += xv[i]; }
  sum = blockReduceSum256(sum, sred);
  float mean = sum * (1.0f / kD);
  float vs = 0.f;
#pragma unroll
  for (int i = 0; i < 4; ++i) { xv[i] -= mean; vs += xv[i] * xv[i]; }
  vs = blockReduceSum256(vs, sred);
  float inv = rsqrtf(vs * (1.0f / kD) + 1e-6f);
  float shv[4], scv[4];
  *(float4*)shv = *(const float4*)&ada[b * 6 * kD + sh_off + d4];
  *(float4*)scv = *(const float4*)&ada[b * 6 * kD + sc_off + d4];
  float uu = 0.f;
#pragma unroll
  for (int i = 0; i < 4; ++i) {
    float u = xv[i] * inv * (1.0f + scv[i]) + shv[i];
    xv[i] = u;
    uu += u * u;
  }
  uu = blockReduceSum256(uu, sred);
  float s = roundtrip_scale(sqrtf(uu));
#pragma unroll
  for (int i = 0; i < 4; ++i) xv[i] *= s;
  store_b4(out + (size_t)tok * kD + d4, xv);
}

// ---------------- bf16 MFMA GEMM: C = A @ Bt^T + bias (round-7 proven) ----------------
template <int OUT_BF16, int KSPLIT>
__global__ __launch_bounds__(256) void k_gemm_bf16(
    const ushort16* __restrict__ A,
    const ushort16* __restrict__ Bt0, const ushort16* __restrict__ Bt1,
    const ushort16* __restrict__ Bt2,
    const float* __restrict__ bias0, const float* __restrict__ bias1,
    const float* __restrict__ bias2,
    void* __restrict__ C0, void* __restrict__ C1, void* __restrict__ C2,
    int M, int N, int K) {
  const ushort16* Bt;
  const float* bias;
  void* C;
  int k_lo, k_hi;
  bool add_bias;
  if (KSPLIT == 1) {
    Bt = (blockIdx.z == 0) ? Bt0 : ((blockIdx.z == 1) ? Bt1 : Bt2);
    bias = (blockIdx.z == 0) ? bias0 : ((blockIdx.z == 1) ? bias1 : bias2);
    C = (blockIdx.z == 0) ? C0 : ((blockIdx.z == 1) ? C1 : C2);
    k_lo = 0; k_hi = K; add_bias = true;
  } else {
    Bt = Bt0; bias = bias0;
    C = (blockIdx.z == 0) ? C0 : C1;
    int kchunk = K / KSPLIT;
    k_lo = blockIdx.z * kchunk; k_hi = k_lo + kchunk;
    add_bias = (blockIdx.z == 0);
  }

  __shared__ __align__(16) ushort16 As[128 * 32];
  __shared__ __align__(16) ushort16 Bs[128 * 32];

  int tid = threadIdx.x;
  int lane = tid & 63;
  int wave = tid >> 6;
  int wm = (wave >> 1) * 64, wn = (wave & 1) * 64;
  int row0 = blockIdx.x * 128, col0 = blockIdx.y * 128;   // rows on x: XCD = row%8

  int e0 = tid * 8;
  int ar0 = e0 >> 5, ac0 = e0 & 31;
  int e1 = e0 + 2048;
  int ar1 = e1 >> 5, ac1 = e1 & 31;
  const ushort16* Ag = A + (size_t)row0 * K;
  const ushort16* Bg = Bt + (size_t)col0 * K;

  floatx4 acc[4][4];
#pragma unroll
  for (int i = 0; i < 4; ++i)
#pragma unroll
    for (int j = 0; j < 4; ++j) acc[i][j] = (floatx4)0.f;

  for (int k0 = k_lo; k0 < k_hi; k0 += 32) {
    async16(Ag + (size_t)ar0 * K + k0 + ac0, As + e0);
    async16(Ag + (size_t)ar1 * K + k0 + ac1, As + e1);
    async16(Bg + (size_t)ar0 * K + k0 + ac0, Bs + e0);
    async16(Bg + (size_t)ar1 * K + k0 + ac1, Bs + e1);
    __syncthreads();

    short8x a[4], b[4];
#pragma unroll
    for (int i = 0; i < 4; ++i) {
      a[i] = *(const short8x*)&As[(wm + i * 16 + (lane & 15)) * 32 + (lane >> 4) * 8];
      b[i] = *(const short8x*)&Bs[(wn + i * 16 + (lane & 15)) * 32 + (lane >> 4) * 8];
    }
#pragma unroll
    for (int i = 0; i < 4; ++i)
#pragma unroll
      for (int j = 0; j < 4; ++j)
        acc[i][j] = __builtin_amdgcn_mfma_f32_16x16x32_bf16(a[i], b[j], acc[i][j], 0, 0, 0);
    __syncthreads();
  }

  float bv[4];
#pragma unroll
  for (int j = 0; j < 4; ++j)
    bv[j] = add_bias ? bias[col0 + wn + j * 16 + (lane & 15)] : 0.f;
  int rowq = (lane >> 4) * 4;
#pragma unroll
  for (int i = 0; i < 4; ++i) {
    int rbase = row0 + wm + i * 16 + rowq;
#pragma unroll
    for (int j = 0; j < 4; ++j) {
      int c = col0 + wn + j * 16 + (lane & 15);
#pragma unroll
      for (int r = 0; r < 4; ++r) {
        float v = acc[i][j][r] + bv[j];
        if (OUT_BF16)
          ((ushort16*)C)[(size_t)(rbase + r) * N + c] = f2b(v);
        else
          ((float*)C)[(size_t)(rbase + r) * N + c] = v;
      }
    }
  }
}

// ---------------- head split (vectorized): thread owns 4 contiguous elems,
// all within head tid>>4. q pre-scaled by 0.125*log2e. ----------------
__global__ __launch_bounds__(256) void k_headsplit_b(const ushort16* __restrict__ q_in,
                                                     ushort16* __restrict__ k_io,
                                                     ushort16* __restrict__ v_io,
                                                     ushort16* __restrict__ qb_out,
                                                     float ratio) {
  __shared__ float sred[4];
  int tok = blockIdx.x;
  int tid = threadIdx.x;
  int d4 = tid * 4;
#pragma unroll
  for (int t = 0; t < 3; ++t) {
    const ushort16* p = (t == 0 ? q_in : (t == 1 ? (const ushort16*)k_io
                                                 : (const ushort16*)v_io)) +
                        (size_t)tok * kD + d4;
    float val[4];
    load_b4(p, val);
    float psq = val[0] * val[0] + val[1] * val[1] + val[2] * val[2] + val[3] * val[3];
    float hsq = redSum16(psq);              // head (tid>>4) sumsq
    float tot = blockReduceSum256(psq, sred);  // full-dim sumsq
    float s1 = roundtrip_scale(sqrtf(tot));
    float c = s1 * ratio;
    float s2 = roundtrip_scale(c * sqrtf(hsq));
    float f = c * s2 * (t == 0 ? (0.125f * LOG2E) : 1.0f);
#pragma unroll
    for (int i = 0; i < 4; ++i) val[i] *= f;
    ushort16* op = (t == 0 ? qb_out : (t == 1 ? k_io : v_io)) + (size_t)tok * kD + d4;
    store_b4(op, val);
    __syncthreads();
  }
}

// ---------------- V transpose: v bf16 [N][D] -> vT bf16 [B*H][64][S],
// with k-permutation pi(s)=(s&15)*2+(s>>4) within each 32-block. ----------------
__global__ __launch_bounds__(256) void k_vtrans_b(const ushort16* __restrict__ v,
                                                  ushort16* __restrict__ vT) {
  __shared__ ushort16 T[64][68];
  int bh = blockIdx.y, b = bh >> 4, h = bh & 15;
  int s0 = blockIdx.x * 64;
  int tid = threadIdx.x;
#pragma unroll
  for (int p = 0; p < 4; ++p) {
    int idx = p * 1024 + tid * 4;
    int r = idx >> 6, d = idx & 63;
    *(uint2*)&T[r][d] = *(const uint2*)&v[(size_t)(b * kS + s0 + r) * kD + h * kHD + d];
  }
  __syncthreads();
#pragma unroll
  for (int p = 0; p < 16; ++p) {
    int idx = p * 256 + tid;
    int d = idx >> 6, c = idx & 63;
    int cp = (c & 32) | ((c & 15) << 1) | ((c >> 4) & 1);  // permuted within 32-block
    vT[((size_t)bh * kHD + d) * kS + s0 + cp] = T[c][d];
  }
}

// ---------------- MFMA flash attention, max-free softmax ----------------
// grid (B*H, S/128): all q-tiles of one head share an XCD -> K/V L2-resident.
__global__ __launch_bounds__(256) void k_attn_mfma(const ushort16* __restrict__ qb,
                                                   const ushort16* __restrict__ kb,
                                                   const ushort16* __restrict__ vT,
                                                   float* __restrict__ outp,
                                                   float ratio2) {
  __shared__ __align__(16) ushort16 Ks[2 * 128 * 32];      // [dsub][key][32]
  __shared__ __align__(16) ushort16 Vs[4 * 64 * 32];       // [ssub][d][32] (permuted k)
  __shared__ __align__(16) ushort16 Ps[4 * 4 * 16 * 40];   // [wave][kk][row16][40pad]
  int bh = blockIdx.x, b = bh >> 4, h = bh & 15;
  int q0 = blockIdx.y * 128;
  int tid = threadIdx.x, lane = tid & 63, wave = tid >> 6;
  int c16 = lane & 15, quad = lane >> 4;
  int wq = wave * 32;

  short8x a_q[2][2];
#pragma unroll
  for (int i = 0; i < 2; ++i)
#pragma unroll
    for (int kk = 0; kk < 2; ++kk)
      a_q[i][kk] = *(const short8x*)&qb[(size_t)(b * kS + q0 + wq + i * 16 + c16) * kD +
                                        h * kHD + kk * 32 + quad * 8];

  short8x ones;
#pragma unroll
  for (int j = 0; j < 8; ++j) ones[j] = (short)0x3F80;  // bf16 1.0

  floatx4 o[2][4], ol[2];
#pragma unroll
  for (int i = 0; i < 2; ++i) {
    ol[i] = (floatx4)0.f;
#pragma unroll
    for (int n = 0; n < 4; ++n) o[i][n] = (floatx4)0.f;
  }

  const ushort16* kbase = kb + ((size_t)b * kS) * kD + h * kHD;
  const ushort16* vbase = vT + (size_t)bh * kHD * kS;

  for (int k0 = 0; k0 < kS; k0 += 128) {
#pragma unroll
    for (int t = 0; t < 2; ++t)
#pragma unroll
      for (int cb = 0; cb < 2; ++cb) {
        int e = cb * 2048 + tid * 8;
        async16(kbase + (size_t)(k0 + (e >> 5)) * kD + t * 32 + (e & 31),
                Ks + t * 4096 + e);
      }
#pragma unroll
    for (int t = 0; t < 4; ++t) {
      int e = tid * 8;
      async16(vbase + (size_t)(e >> 5) * kS + k0 + t * 32 + (e & 31),
              Vs + t * 2048 + e);
    }
    __syncthreads();

#pragma unroll
    for (int i = 0; i < 2; ++i) {
      floatx4 s[8];
#pragma unroll
      for (int n = 0; n < 8; ++n) s[n] = (floatx4)0.f;
#pragma unroll
      for (int kkd = 0; kkd < 2; ++kkd)
#pragma unroll
        for (int n = 0; n < 8; ++n) {
          short8x bk = *(const short8x*)&Ks[kkd * 4096 + (n * 16 + c16) * 32 + quad * 8];
          s[n] = __builtin_amdgcn_mfma_f32_16x16x32_bf16(a_q[i][kkd], bk, s[n], 0, 0, 0);
        }

      // p = exp2(s) (log2e pre-folded into q); packed b32 writes, permuted k
#pragma unroll
      for (int r = 0; r < 4; ++r) {
#pragma unroll
        for (int j = 0; j < 4; ++j) {
          uint32 u0 = (uint32)f2b(exp2f(s[2 * j][r]));
          uint32 u1 = (uint32)f2b(exp2f(s[2 * j + 1][r]));
          *(uint32*)&Ps[(((wave * 4 + j) * 16) + (quad * 4 + r)) * 40 + c16 * 2] =
              u0 | (u1 << 16);
        }
      }

      // o += P @ V ; l += P @ ones
#pragma unroll
      for (int kk = 0; kk < 4; ++kk) {
        short8x ap = *(const short8x*)&Ps[(((wave * 4 + kk) * 16) + c16) * 40 + quad * 8];
#pragma unroll
        for (int n = 0; n < 4; ++n) {
          short8x bv = *(const short8x*)&Vs[kk * 2048 + (n * 16 + c16) * 32 + quad * 8];
          o[i][n] = __builtin_amdgcn_mfma_f32_16x16x32_bf16(ap, bv, o[i][n], 0, 0, 0);
        }
        ol[i] = __builtin_amdgcn_mfma_f32_16x16x32_bf16(ap, ones, ol[i], 0, 0, 0);
      }
    }
    __syncthreads();
  }

#pragma unroll
  for (int i = 0; i < 2; ++i)
#pragma unroll
    for (int r = 0; r < 4; ++r) {
      float invl = 1.0f / ol[i][r];
      float w[4];
      float pssq = 0.f;
#pragma unroll
      for (int n = 0; n < 4; ++n) { w[n] = o[i][n][r] * invl; pssq += w[n] * w[n]; }
      float ssq = redSum16(pssq);
      float coef = roundtrip_scale(sqrtf(ssq)) * ratio2;
      int row = b * kS + q0 + wq + i * 16 + quad * 4 + r;
#pragma unroll
      for (int n = 0; n < 4; ++n)
        outp[(size_t)row * kD + h * kHD + n * 16 + c16] = coef * w[n];
    }
}

// ---------------- roundtrip scale, fp32 in -> bf16 out (vectorized) ----------------
template <int WIDTH>
__global__ __launch_bounds__(256) void k_rt_scale_f2b(const float* __restrict__ p,
                                                      ushort16* __restrict__ out) {
  __shared__ float sred[4];
  constexpr int PER = WIDTH / 1024;   // float4 groups per thread
  size_t base = (size_t)blockIdx.x * WIDTH;
  float v[PER][4];
  float ss = 0.f;
#pragma unroll
  for (int i = 0; i < PER; ++i) {
    *(float4*)v[i] = *(const float4*)&p[base + i * 1024 + threadIdx.x * 4];
#pragma unroll
    for (int j = 0; j < 4; ++j) ss += v[i][j] * v[i][j];
  }
  ss = blockReduceSum256(ss, sred);
  float s = roundtrip_scale(sqrtf(ss));
#pragma unroll
  for (int i = 0; i < PER; ++i) {
#pragma unroll
    for (int j = 0; j < 4; ++j) v[i][j] *= s;
    store_b4(out + base + i * 1024 + threadIdx.x * 4, v[i]);
  }
}

// ---------------- roundtrip scale, bf16 in/out in place (b128 vectorized) ----------------
template <int WIDTH>
__global__ __launch_bounds__(256) void k_rt_scale_b2b(ushort16* __restrict__ p) {
  __shared__ float sred[4];
  constexpr int PER = WIDTH / 1024;   // 4-elem groups per thread
  size_t base = (size_t)blockIdx.x * WIDTH;
  float v[PER][4];
  float ss = 0.f;
#pragma unroll
  for (int i = 0; i < PER; ++i) {
    load_b4(p + base + i * 1024 + threadIdx.x * 4, v[i]);
#pragma unroll
    for (int j = 0; j < 4; ++j) ss += v[i][j] * v[i][j];
  }
  ss = blockReduceSum256(ss, sred);
  float s = roundtrip_scale(sqrtf(ss));
#pragma unroll
  for (int i = 0; i < PER; ++i) {
#pragma unroll
    for (int j = 0; j < 4; ++j) v[i][j] *= s;
    store_b4(p + base + i * 1024 + threadIdx.x * 4, v[i]);
  }
}

// ---------------- mobius epilogue core (vectorized helpers) ----------------
__device__ __forceinline__ void mobius_body(float xv[4], float tv[4],
                                            const float* gp, int d4,
                                            float* sred, float outv[4]) {
  float ss = tv[0] * tv[0] + tv[1] * tv[1] + tv[2] * tv[2] + tv[3] * tv[3];
  ss = blockReduceSum256(ss, sred);
  float s5 = roundtrip_scale(sqrtf(ss));
  float gv[4];
  *(float4*)gv = *(const float4*)&gp[d4];
  float at2 = 0.f;
#pragma unroll
  for (int i = 0; i < 4; ++i) {
    float a = gv[i] * s5 * tv[i];
    tv[i] = a;
    at2 += a * a;
  }
  at2 = blockReduceSum256(at2, sred);
  float nyraw = sqrtf(at2);
  float sy = expmap0_scale(nyraw);
  float ynorm = sy * nyraw;
  float y2 = ynorm * ynorm;
  float x2p = 0.f, xyp = 0.f;
#pragma unroll
  for (int i = 0; i < 4; ++i) {
    float y = sy * tv[i];
    tv[i] = y;
    x2p += xv[i] * xv[i];
    xyp += xv[i] * y;
  }
  float x2 = blockReduceSum256(x2p, sred);
  float xy = blockReduceSum256(xyp, sred);
  float cx = 1.0f + 2.0f * xy + y2;
  float cy = 1.0f - x2;
  float den = fmaxf(1.0f + 2.0f * xy + x2 * y2, EPSF);
  float invden = 1.0f / den;
#pragma unroll
  for (int i = 0; i < 4; ++i) outv[i] = (cx * xv[i] + cy * tv[i]) * invden;
}

// final epilogue: out = mobius(xres, expmap0(g*rt(p0+p1)))
__global__ __launch_bounds__(256) void k_epilogue2(const float* __restrict__ xres,
                                                   const float* __restrict__ ot0,
                                                   const float* __restrict__ ot1,
                                                   const float* __restrict__ ada,
                                                   int g_off,
                                                   float* __restrict__ out) {
  __shared__ float sred[4];
  int tok = blockIdx.x;
  int b = tok >> 10;
  size_t base = (size_t)tok * kD;
  int d4 = threadIdx.x * 4;
  float xv[4], tv[4], t0[4], t1[4];
  *(float4*)t0 = *(const float4*)&ot0[base + d4];
  *(float4*)t1 = *(const float4*)&ot1[base + d4];
  *(float4*)xv = *(const float4*)&xres[base + d4];
#pragma unroll
  for (int i = 0; i < 4; ++i) tv[i] = t0[i] + t1[i];
  float outv[4];
  mobius_body(xv, tv, ada + b * 6 * kD + g_off, d4, sred, outv);
  *(float4*)&out[base + d4] = *(float4*)outv;
}

// fused: x_mid = mobius(x, msa partials) -> xmid_out (f32), then
// lx2 = rt(layernorm(logmap0(x_mid))*(1+sc)+sh) -> lx2_out (bf16)
__global__ __launch_bounds__(256) void k_epi_pre(const float* __restrict__ xres,
                                                 const float* __restrict__ ot0,
                                                 const float* __restrict__ ot1,
                                                 const float* __restrict__ ada,
                                                 float* __restrict__ xmid_out,
                                                 ushort16* __restrict__ lx2_out) {
  __shared__ float sred[4];
  int tok = blockIdx.x;
  int b = tok >> 10;
  size_t base = (size_t)tok * kD;
  int d4 = threadIdx.x * 4;
  float xv[4], tv[4], t0[4], t1[4];
  *(float4*)t0 = *(const float4*)&ot0[base + d4];
  *(float4*)t1 = *(const float4*)&ot1[base + d4];
  *(float4*)xv = *(const float4*)&xres[base + d4];
#pragma unroll
  for (int i = 0; i < 4; ++i) tv[i] = t0[i] + t1[i];
  float xm[4];
  mobius_body(xv, tv, ada + b * 6 * kD + 2 * kD, d4, sred, xm);
  *(float4*)&xmid_out[base + d4] = *(float4*)xm;

  // prenorm (mlp) on xm
  float ss = xm[0] * xm[0] + xm[1] * xm[1] + xm[2] * xm[2] + xm[3] * xm[3];
  ss = blockReduceSum256(ss, sred);
  float sl = logmap0_scale(sqrtf(ss));
  float sum = 0.f;
#pragma unroll
  for (int i = 0; i < 4; ++i) { xm[i] *= sl; sum += xm[i]; }
  sum = blockReduceSum256(sum, sred);
  float mean = sum * (1.0f / kD);
  float vs = 0.f;
#pragma unroll
  for (int i = 0; i < 4; ++i) { xm[i] -= mean; vs += xm[i] * xm[i]; }
  vs = blockReduceSum256(vs, sred);
  float inv = rsqrtf(vs * (1.0f / kD) + 1e-6f);
  float shv[4], scv[4];
  *(float4*)shv = *(const float4*)&ada[b * 6 * kD + 3 * kD + d4];
  *(float4*)scv = *(const float4*)&ada[b * 6 * kD + 4 * kD + d4];
  float uu = 0.f;
#pragma unroll
  for (int i = 0; i < 4; ++i) {
    float u = xm[i] * inv * (1.0f + scv[i]) + shv[i];
    xm[i] = u;
    uu += u * u;
  }
  uu = blockReduceSum256(uu, sred);
  float s = roundtrip_scale(sqrtf(uu));
#pragma unroll
  for (int i = 0; i < 4; ++i) xm[i] *= s;
  store_b4(lx2_out + base + d4, xm);
}

// ---------------------------------------------------------------------------
extern "C" void kernel_launch(void* const* d_in, const int* in_sizes, int n_in,
                              void* d_out, int out_size, void* d_ws, size_t ws_size,
                              hipStream_t stream) {
  const float* x     = (const float*)d_in[0];
  const float* t_emb = (const float*)d_in[1];
  const float* w_q = (const float*)d_in[2];  const float* b_q = (const float*)d_in[3];
  const float* w_k = (const float*)d_in[4];  const float* b_k = (const float*)d_in[5];
  const float* w_v = (const float*)d_in[6];  const float* b_v = (const float*)d_in[7];
  const float* w_o = (const float*)d_in[8];  const float* b_o = (const float*)d_in[9];
  const float* w_f1 = (const float*)d_in[10]; const float* b_f1 = (const float*)d_in[11];
  const float* w_f2 = (const float*)d_in[12]; const float* b_f2 = (const float*)d_in[13];
  const float* w_ada = (const float*)d_in[14]; const float* b_ada = (const float*)d_in[15];
  float* out = (float*)d_out;

  constexpr size_t ND = (size_t)kN * kD;    // 4 M
  constexpr size_t NF = (size_t)kN * kFF;   // 16 M
  constexpr size_t DD = (size_t)kD * kD;    // 1 M

  float* ws   = (float*)d_ws;
  float* ada  = ws;                 // 24576 f32
  float* qt   = ada + 6 * kD * kB;  // ND f32 (split-K partial 0)
  float* kt   = qt + ND;            // ND f32 (attn out; f2 partial 1)
  float* vt   = kt + ND;            // ND f32 (o partial 1 -> x_mid in place)
  ushort16* qbA = (ushort16*)(vt + ND);   // ND bf16 (lx / qb / rt(ao) / lx2)
  ushort16* kb  = qbA + ND;               // ND bf16 (q raw -> vT)
  ushort16* vTb = kb + ND;                // ND bf16 (k raw -> k scaled)
  ushort16* actB = vTb + ND;              // NF bf16 (v raw/scaled; h1)
  ushort16* wqT  = actB + NF;             // DD bf16 each
  ushort16* wkT  = wqT + DD;
  ushort16* wvT  = wkT + DD;
  ushort16* woT  = wvT + DD;
  ushort16* wf1T = woT + DD;              // FF*D
  ushort16* wf2T = wf1T + (size_t)kD * kFF;

  double bn = exp(lgamma(512.0) + lgamma(0.5) - lgamma(512.5));
  double bh = exp(lgamma(32.0) + lgamma(0.5) - lgamma(32.5));
  float R1 = (float)(bh / bn);
  float R2 = (float)(bn / bh);

  // 0) weight transposes + cast to bf16 [N][K]
  k_transpose4<<<dim3(16, 16, 4), 256, 0, stream>>>(w_q, w_k, w_v, w_o,
                                                    wqT, wkT, wvT, woT);
  k_transpose_bf16<<<dim3(64, 16), 256, 0, stream>>>(w_f1, wf1T, kD, kFF);
  k_transpose_bf16<<<dim3(16, 64), 256, 0, stream>>>(w_f2, wf2T, kFF, kD);
  // 1) ada (K-chunked GEMV)
  k_ada<<<dim3(6 * kD / 64, kB), 256, 0, stream>>>(t_emb, w_ada, b_ada, ada);
  // 2) prenorm (msa): lx -> qbA (bf16)
  k_prenorm<<<kN, 256, 0, stream>>>(x, ada, 0 * kD, 1 * kD, qbA);
  // 3) q,k,v projections, bf16 out: q->kb, k->vTb, v->actB
  k_gemm_bf16<1, 1><<<dim3(kN / 128, kD / 128, 3), 256, 0, stream>>>(
      qbA, wqT, wkT, wvT, b_q, b_k, b_v, kb, vTb, actB, kN, kD, kD);
  // 4) head split (bf16): qb->qbA (pre-scaled 0.125*log2e), k in vTb, v in actB
  k_headsplit_b<<<kN, 256, 0, stream>>>(kb, vTb, actB, qbA, R1);
  // 5) V transpose (k-permuted): actB -> kb ([B*H][64][S] bf16)
  k_vtrans_b<<<dim3(kS / 64, kB * kH), 256, 0, stream>>>(actB, kb);
  // 6) MFMA flash attention (max-free) -> kt; grid (bh, qtile) for K/V L2 locality
  k_attn_mfma<<<dim3(kB * kH, kS / 128), 256, 0, stream>>>(qbA, vTb, kb, kt, R2);
  // 7) full-dim roundtrip -> qbA (bf16)
  k_rt_scale_f2b<kD><<<kN, 256, 0, stream>>>(kt, qbA);
  // 8) o projection, split-K=2 -> partials qt (z=0, +bias) and vt (z=1)
  k_gemm_bf16<0, 2><<<dim3(kN / 128, kD / 128, 2), 256, 0, stream>>>(
      qbA, woT, woT, woT, b_o, b_o, b_o, qt, vt, vt, kN, kD, kD);
  // 9+10) fused mobius epilogue (msa) + prenorm (mlp): vt <- x_mid, qbA <- lx2
  k_epi_pre<<<kN, 256, 0, stream>>>(x, qt, vt, ada, vt, qbA);
  // 11) f1 -> actB (bf16 direct)
  k_gemm_bf16<1, 1><<<dim3(kN / 128, kFF / 128, 1), 256, 0, stream>>>(
      qbA, wf1T, wf1T, wf1T, b_f1, b_f1, b_f1, actB, actB, actB, kN, kFF, kD);
  // 12) roundtrip on h1 (bf16 in place)
  k_rt_scale_b2b<kFF><<<kN, 256, 0, stream>>>(actB);
  // 13) f2, split-K=2 -> partials qt (z=0, +bias) and kt (z=1)
  k_gemm_bf16<0, 2><<<dim3(kN / 128, kD / 128, 2), 256, 0, stream>>>(
      actB, wf2T, wf2T, wf2T, b_f2, b_f2, b_f2, qt, kt, kt, kN, kD, kFF);
  // 14) mobius epilogue (mlp): out = mobius(vt, qt+kt)
  k_epilogue2<<<kN, 256, 0, stream>>>(vt, qt, kt, ada, 5 * kD, out);

  (void)in_sizes; (void)n_in; (void)out_size; (void)ws_size;
}

// Round 9
// 451.796 us; speedup vs baseline: 1.2387x; 1.0282x over previous
//
#include <hip/hip_runtime.h>
#include <cmath>

// ---------------------------------------------------------------------------
// Poincare transformer layer. Round 9:
//  (a) XOR-swizzled LDS staging for all MFMA tiles (GEMM As/Bs, attn Ks/Vs):
//      source chunk permuted by (row>>1)&3, un-permuted at ds_read_b128 ->
//      2-way banks (free) instead of ~8-way.
//  (b) row-scale commutation: rt(|row|) scales commute through GEMMs, so the
//      two full-tensor roundtrip passes are replaced by tiny norm-only
//      k_rowscale kernels + per-row scaling in the o/f2 GEMM epilogues.
//      Attention writes tangent bf16 in-place into its q buffer.
//  (c) split-K second partials stored bf16 (o-proj, f2).
// ---------------------------------------------------------------------------

constexpr int kD  = 1024;
constexpr int kH  = 16;
constexpr int kHD = 64;
constexpr int kFF = 4096;
constexpr int kB  = 4;
constexpr int kS  = 1024;
constexpr int kN  = kB * kS;   // 4096 tokens

#define EPSF 1e-7f
#define MTAF (1.0f - 1e-5f)
#define LOG2E 1.4426950408889634f

typedef unsigned int uint32;
typedef unsigned short ushort16;
typedef __attribute__((ext_vector_type(8))) short short8x;
typedef __attribute__((ext_vector_type(4))) float floatx4;

// ---------------- bf16 helpers ----------------
__device__ __forceinline__ ushort16 f2b(float f) {
  union { float f; uint32 u; } x; x.f = f;
  uint32 r = x.u + 0x7fffu + ((x.u >> 16) & 1u);   // RNE
  return (ushort16)(r >> 16);
}
__device__ __forceinline__ float b2f(ushort16 u) {
  union { uint32 u; float f; } x; x.u = ((uint32)u) << 16;
  return x.f;
}
__device__ __forceinline__ void load_b4(const ushort16* p, float v[4]) {
  uint2 u = *(const uint2*)p;
  v[0] = b2f((ushort16)(u.x & 0xffff)); v[1] = b2f((ushort16)(u.x >> 16));
  v[2] = b2f((ushort16)(u.y & 0xffff)); v[3] = b2f((ushort16)(u.y >> 16));
}
__device__ __forceinline__ void store_b4(ushort16* p, const float v[4]) {
  uint2 u;
  u.x = (uint32)f2b(v[0]) | ((uint32)f2b(v[1]) << 16);
  u.y = (uint32)f2b(v[2]) | ((uint32)f2b(v[3]) << 16);
  *(uint2*)p = u;
}

// ---------------- math helpers ----------------
__device__ __forceinline__ float atanh_clipped(float n) {
  float c = fminf(n, MTAF);
  return 0.5f * logf((1.0f + c) / (1.0f - c));
}
__device__ __forceinline__ float logmap0_scale(float nraw) {
  float n = fmaxf(nraw, EPSF);
  return atanh_clipped(n) / n;
}
__device__ __forceinline__ float expmap0_scale(float nraw) {
  float n = fmaxf(nraw, EPSF);
  return tanhf(n) / n;
}
__device__ __forceinline__ float roundtrip_scale(float nraw) {
  float nu = fmaxf(nraw, EPSF);
  float se = tanhf(nu) / nu;
  float nb = fmaxf(se * nraw, EPSF);
  float sl = atanh_clipped(nb) / nb;
  return sl * se;
}

// ---------------- reductions ----------------
__device__ __forceinline__ float blockReduceSum256(float v, float* s4) {
#pragma unroll
  for (int o = 32; o > 0; o >>= 1) v += __shfl_xor(v, o);
  int wave = threadIdx.x >> 6;
  if ((threadIdx.x & 63) == 0) s4[wave] = v;
  __syncthreads();
  float r = s4[0] + s4[1] + s4[2] + s4[3];
  __syncthreads();
  return r;
}
__device__ __forceinline__ float redSum16(float v) {
#pragma unroll
  for (int o = 8; o > 0; o >>= 1) v += __shfl_xor(v, o);
  return v;
}

// ---------------- async global->LDS, 16 bytes/lane ----------------
__device__ __forceinline__ void async16(const void* g, void* l) {
  __builtin_amdgcn_global_load_lds(
      (const __attribute__((address_space(1))) uint32*)g,
      (__attribute__((address_space(3))) uint32*)l, 16, 0, 0);
}

// ---------------- weight transpose + cast: src [K][N] f32 -> dst [N][K] bf16 ----
__device__ __forceinline__ void transpose_tile(const float* __restrict__ src,
                                               ushort16* __restrict__ dst,
                                               int K, int N, int n0, int k0) {
  __shared__ float T[64][65];
  int tid = threadIdx.x;
#pragma unroll
  for (int p = 0; p < 4; ++p) {
    int idx = p * 1024 + tid * 4;
    int r = idx >> 6, c = idx & 63;
    float4 t = *(const float4*)&src[(size_t)(k0 + r) * N + n0 + c];
    T[r][c] = t.x; T[r][c + 1] = t.y; T[r][c + 2] = t.z; T[r][c + 3] = t.w;
  }
  __syncthreads();
#pragma unroll
  for (int p = 0; p < 4; ++p) {
    int idx = p * 1024 + tid * 4;
    int r = idx >> 6, c = idx & 63;
    float v[4] = {T[c][r], T[c + 1][r], T[c + 2][r], T[c + 3][r]};
    store_b4(&dst[(size_t)(n0 + r) * K + k0 + c], v);
  }
}
__global__ __launch_bounds__(256) void k_transpose_bf16(const float* __restrict__ src,
                                                        ushort16* __restrict__ dst,
                                                        int K, int N) {
  transpose_tile(src, dst, K, N, blockIdx.x * 64, blockIdx.y * 64);
}
__global__ __launch_bounds__(256) void k_transpose4(
    const float* __restrict__ s0, const float* __restrict__ s1,
    const float* __restrict__ s2, const float* __restrict__ s3,
    ushort16* __restrict__ d0, ushort16* __restrict__ d1,
    ushort16* __restrict__ d2, ushort16* __restrict__ d3) {
  const float* src = (blockIdx.z == 0) ? s0 : (blockIdx.z == 1) ? s1
                    : (blockIdx.z == 2) ? s2 : s3;
  ushort16* dst = (blockIdx.z == 0) ? d0 : (blockIdx.z == 1) ? d1
                 : (blockIdx.z == 2) ? d2 : d3;
  transpose_tile(src, dst, kD, kD, blockIdx.x * 64, blockIdx.y * 64);
}

// ---------------- ada = t_emb @ w_ada + b_ada (K-chunked GEMV) ----------------
__global__ __launch_bounds__(256) void k_ada(const float* __restrict__ t_emb,
                                             const float* __restrict__ w_ada,
                                             const float* __restrict__ b_ada,
                                             float* __restrict__ ada) {
  __shared__ float te[kD];
  __shared__ float part[4][64];
  int b = blockIdx.y;
  int tid = threadIdx.x;
  {
    float4 t = *(const float4*)&t_emb[b * kD + tid * 4];
    te[tid * 4] = t.x; te[tid * 4 + 1] = t.y; te[tid * 4 + 2] = t.z; te[tid * 4 + 3] = t.w;
  }
  __syncthreads();
  int c = tid & 63, kc = tid >> 6;
  int col = blockIdx.x * 64 + c;
  float acc = 0.f;
#pragma unroll 8
  for (int k = kc * 256; k < kc * 256 + 256; ++k)
    acc += te[k] * w_ada[(size_t)k * (6 * kD) + col];
  part[kc][c] = acc;
  __syncthreads();
  if (tid < 64)
    ada[b * 6 * kD + blockIdx.x * 64 + tid] =
        part[0][tid] + part[1][tid] + part[2][tid] + part[3][tid] +
        b_ada[blockIdx.x * 64 + tid];
}

// ---------------- prenorm -> bf16 GEMM input (vectorized) ----------------
__global__ __launch_bounds__(256) void k_prenorm(const float* __restrict__ x,
                                                 const float* __restrict__ ada,
                                                 int sh_off, int sc_off,
                                                 ushort16* __restrict__ out) {
  __shared__ float sred[4];
  int tok = blockIdx.x;
  int b = tok >> 10;
  int d4 = threadIdx.x * 4;
  float xv[4];
  *(float4*)xv = *(const float4*)&x[(size_t)tok * kD + d4];
  float ss = xv[0] * xv[0] + xv[1] * xv[1] + xv[2] * xv[2] + xv[3] * xv[3];
  ss = blockReduceSum256(ss, sred);
  float sl = logmap0_scale(sqrtf(ss));
  float sum = 0.f;
#pragma unroll
  for (int i = 0; i < 4; ++i) { xv[i] *= sl; sum += xv[i]; }
  sum = blockReduceSum256(sum, sred);
  float mean = sum * (1.0f / kD);
  float vs = 0.f;
#pragma unroll
  for (int i = 0; i < 4; ++i) { xv[i] -= mean; vs += xv[i] * xv[i]; }
  vs = blockReduceSum256(vs, sred);
  float inv = rsqrtf(vs * (1.0f / kD) + 1e-6f);
  float shv[4], scv[4];
  *(float4*)shv = *(const float4*)&ada[b * 6 * kD + sh_off + d4];
  *(float4*)scv = *(const float4*)&ada[b * 6 * kD + sc_off + d4];
  float uu = 0.f;
#pragma unroll
  for (int i = 0; i < 4; ++i) {
    float u = xv[i] * inv * (1.0f + scv[i]) + shv[i];
    xv[i] = u;
    uu += u * u;
  }
  uu = blockReduceSum256(uu, sred);
  float s = roundtrip_scale(sqrtf(uu));
#pragma unroll
  for (int i = 0; i < 4; ++i) xv[i] *= s;
  store_b4(out + (size_t)tok * kD + d4, xv);
}

// ---------------- bf16 MFMA GEMM: C = rowscale ∘ (A @ Bt^T) + bias ----------------
// XOR-swizzled staging: source chunk cb ^= (row>>1)&3; reads un-permute.
// KSPLIT==1: z selects (Bt,bias,C) triple, C dtype per OUT_BF16.
// KSPLIT==2: z = K-half; z=0 -> C0 f32 (+bias), z=1 -> C1 bf16 (no bias).
template <int OUT_BF16, int KSPLIT>
__global__ __launch_bounds__(256) void k_gemm_bf16(
    const ushort16* __restrict__ A,
    const ushort16* __restrict__ Bt0, const ushort16* __restrict__ Bt1,
    const ushort16* __restrict__ Bt2,
    const float* __restrict__ bias0, const float* __restrict__ bias1,
    const float* __restrict__ bias2,
    const float* __restrict__ rowscale,
    void* __restrict__ C0, void* __restrict__ C1, void* __restrict__ C2,
    int M, int N, int K) {
  const ushort16* Bt;
  const float* bias;
  void* C;
  int k_lo, k_hi;
  bool add_bias;
  if (KSPLIT == 1) {
    Bt = (blockIdx.z == 0) ? Bt0 : ((blockIdx.z == 1) ? Bt1 : Bt2);
    bias = (blockIdx.z == 0) ? bias0 : ((blockIdx.z == 1) ? bias1 : bias2);
    C = (blockIdx.z == 0) ? C0 : ((blockIdx.z == 1) ? C1 : C2);
    k_lo = 0; k_hi = K; add_bias = true;
  } else {
    Bt = Bt0; bias = bias0;
    C = (blockIdx.z == 0) ? C0 : C1;
    int kchunk = K / KSPLIT;
    k_lo = blockIdx.z * kchunk; k_hi = k_lo + kchunk;
    add_bias = (blockIdx.z == 0);
  }

  __shared__ __align__(16) ushort16 As[128 * 32];
  __shared__ __align__(16) ushort16 Bs[128 * 32];

  int tid = threadIdx.x;
  int lane = tid & 63;
  int wave = tid >> 6;
  int wm = (wave >> 1) * 64, wn = (wave & 1) * 64;
  int row0 = blockIdx.x * 128, col0 = blockIdx.y * 128;   // rows on x: XCD = row%8

  // swizzled staging coords
  int e0 = tid * 8;
  int ar0 = e0 >> 5;
  int ac0 = ((((e0 >> 3) & 3) ^ ((ar0 >> 1) & 3)) << 3);
  int e1 = e0 + 2048;
  int ar1 = e1 >> 5;
  int ac1 = ((((e1 >> 3) & 3) ^ ((ar1 >> 1) & 3)) << 3);
  const ushort16* Ag = A + (size_t)row0 * K;
  const ushort16* Bg = Bt + (size_t)col0 * K;

  int c16 = lane & 15, quad = lane >> 4;
  int sw = (lane >> 1) & 3;           // == (c16>>1)&3
  int cbp = ((quad ^ sw) << 3);       // physical chunk for logical chunk 'quad'

  floatx4 acc[4][4];
#pragma unroll
  for (int i = 0; i < 4; ++i)
#pragma unroll
    for (int j = 0; j < 4; ++j) acc[i][j] = (floatx4)0.f;

  for (int k0 = k_lo; k0 < k_hi; k0 += 32) {
    async16(Ag + (size_t)ar0 * K + k0 + ac0, As + e0);
    async16(Ag + (size_t)ar1 * K + k0 + ac1, As + e1);
    async16(Bg + (size_t)ar0 * K + k0 + ac0, Bs + e0);
    async16(Bg + (size_t)ar1 * K + k0 + ac1, Bs + e1);
    __syncthreads();

    short8x a[4], b[4];
#pragma unroll
    for (int i = 0; i < 4; ++i) {
      a[i] = *(const short8x*)&As[(wm + i * 16 + c16) * 32 + cbp];
      b[i] = *(const short8x*)&Bs[(wn + i * 16 + c16) * 32 + cbp];
    }
#pragma unroll
    for (int i = 0; i < 4; ++i)
#pragma unroll
      for (int j = 0; j < 4; ++j)
        acc[i][j] = __builtin_amdgcn_mfma_f32_16x16x32_bf16(a[i], b[j], acc[i][j], 0, 0, 0);
    __syncthreads();
  }

  float bv[4];
#pragma unroll
  for (int j = 0; j < 4; ++j)
    bv[j] = add_bias ? bias[col0 + wn + j * 16 + c16] : 0.f;
  int rowq = quad * 4;
#pragma unroll
  for (int i = 0; i < 4; ++i) {
    int rbase = row0 + wm + i * 16 + rowq;
    float rs4[4];
#pragma unroll
    for (int r = 0; r < 4; ++r) rs4[r] = rowscale ? rowscale[rbase + r] : 1.0f;
#pragma unroll
    for (int j = 0; j < 4; ++j) {
      int c = col0 + wn + j * 16 + c16;
#pragma unroll
      for (int r = 0; r < 4; ++r) {
        float v = acc[i][j][r] * rs4[r] + bv[j];
        if (KSPLIT == 2) {
          if (blockIdx.z == 0) ((float*)C)[(size_t)(rbase + r) * N + c] = v;
          else ((ushort16*)C)[(size_t)(rbase + r) * N + c] = f2b(v);
        } else if (OUT_BF16) {
          ((ushort16*)C)[(size_t)(rbase + r) * N + c] = f2b(v);
        } else {
          ((float*)C)[(size_t)(rbase + r) * N + c] = v;
        }
      }
    }
  }
}

// ---------------- head split (vectorized) ----------------
__global__ __launch_bounds__(256) void k_headsplit_b(const ushort16* __restrict__ q_in,
                                                     ushort16* __restrict__ k_io,
                                                     ushort16* __restrict__ v_io,
                                                     ushort16* __restrict__ qb_out,
                                                     float ratio) {
  __shared__ float sred[4];
  int tok = blockIdx.x;
  int tid = threadIdx.x;
  int d4 = tid * 4;
#pragma unroll
  for (int t = 0; t < 3; ++t) {
    const ushort16* p = (t == 0 ? q_in : (t == 1 ? (const ushort16*)k_io
                                                 : (const ushort16*)v_io)) +
                        (size_t)tok * kD + d4;
    float val[4];
    load_b4(p, val);
    float psq = val[0] * val[0] + val[1] * val[1] + val[2] * val[2] + val[3] * val[3];
    float hsq = redSum16(psq);
    float tot = blockReduceSum256(psq, sred);
    float s1 = roundtrip_scale(sqrtf(tot));
    float c = s1 * ratio;
    float s2 = roundtrip_scale(c * sqrtf(hsq));
    float f = c * s2 * (t == 0 ? (0.125f * LOG2E) : 1.0f);
#pragma unroll
    for (int i = 0; i < 4; ++i) val[i] *= f;
    ushort16* op = (t == 0 ? qb_out : (t == 1 ? k_io : v_io)) + (size_t)tok * kD + d4;
    store_b4(op, val);
    __syncthreads();
  }
}

// ---------------- V transpose with k-permutation pi(s)=(s&15)*2+(s>>4) ----------------
__global__ __launch_bounds__(256) void k_vtrans_b(const ushort16* __restrict__ v,
                                                  ushort16* __restrict__ vT) {
  __shared__ ushort16 T[64][68];
  int bh = blockIdx.y, b = bh >> 4, h = bh & 15;
  int s0 = blockIdx.x * 64;
  int tid = threadIdx.x;
#pragma unroll
  for (int p = 0; p < 4; ++p) {
    int idx = p * 1024 + tid * 4;
    int r = idx >> 6, d = idx & 63;
    *(uint2*)&T[r][d] = *(const uint2*)&v[(size_t)(b * kS + s0 + r) * kD + h * kHD + d];
  }
  __syncthreads();
#pragma unroll
  for (int p = 0; p < 16; ++p) {
    int idx = p * 256 + tid;
    int d = idx >> 6, c = idx & 63;
    int cp = (c & 32) | ((c & 15) << 1) | ((c >> 4) & 1);
    vT[((size_t)bh * kHD + d) * kS + s0 + cp] = T[c][d];
  }
}

// ---------------- MFMA flash attention, max-free; writes bf16 T IN PLACE ----------------
// Block (bh, qtile) reads exactly the qb region it later overwrites (a_q loaded
// at start); no other block touches that (rows, head) region.
__global__ __launch_bounds__(256) void k_attn_mfma(ushort16* __restrict__ qb,
                                                   const ushort16* __restrict__ kb,
                                                   const ushort16* __restrict__ vT,
                                                   float ratio2) {
  __shared__ __align__(16) ushort16 Ks[2 * 128 * 32];      // [dsub][key][32] swizzled
  __shared__ __align__(16) ushort16 Vs[4 * 64 * 32];       // [ssub][d][32] swizzled
  __shared__ __align__(16) ushort16 Ps[4 * 4 * 16 * 40];   // [wave][kk][row16][40pad]
  int bh = blockIdx.x, b = bh >> 4, h = bh & 15;
  int q0 = blockIdx.y * 128;
  int tid = threadIdx.x, lane = tid & 63, wave = tid >> 6;
  int c16 = lane & 15, quad = lane >> 4;
  int sw = (lane >> 1) & 3;
  int cbp = ((quad ^ sw) << 3);
  int wq = wave * 32;

  short8x a_q[2][2];
#pragma unroll
  for (int i = 0; i < 2; ++i)
#pragma unroll
    for (int kk = 0; kk < 2; ++kk)
      a_q[i][kk] = *(const short8x*)&qb[(size_t)(b * kS + q0 + wq + i * 16 + c16) * kD +
                                        h * kHD + kk * 32 + quad * 8];

  short8x ones;
#pragma unroll
  for (int j = 0; j < 8; ++j) ones[j] = (short)0x3F80;  // bf16 1.0

  floatx4 o[2][4], ol[2];
#pragma unroll
  for (int i = 0; i < 2; ++i) {
    ol[i] = (floatx4)0.f;
#pragma unroll
    for (int n = 0; n < 4; ++n) o[i][n] = (floatx4)0.f;
  }

  const ushort16* kbase = kb + ((size_t)b * kS) * kD + h * kHD;
  const ushort16* vbase = vT + (size_t)bh * kHD * kS;

  for (int k0 = 0; k0 < kS; k0 += 128) {
#pragma unroll
    for (int t = 0; t < 2; ++t)
#pragma unroll
      for (int cb2 = 0; cb2 < 2; ++cb2) {
        int e = cb2 * 2048 + tid * 8;
        int key = e >> 5;
        int col = ((((e >> 3) & 3) ^ ((key >> 1) & 3)) << 3);
        async16(kbase + (size_t)(k0 + key) * kD + t * 32 + col, Ks + t * 4096 + e);
      }
#pragma unroll
    for (int t = 0; t < 4; ++t) {
      int e = tid * 8;
      int dd = e >> 5;
      int col = ((((e >> 3) & 3) ^ ((dd >> 1) & 3)) << 3);
      async16(vbase + (size_t)dd * kS + k0 + t * 32 + col, Vs + t * 2048 + e);
    }
    __syncthreads();

#pragma unroll
    for (int i = 0; i < 2; ++i) {
      floatx4 s[8];
#pragma unroll
      for (int n = 0; n < 8; ++n) s[n] = (floatx4)0.f;
#pragma unroll
      for (int kkd = 0; kkd < 2; ++kkd)
#pragma unroll
        for (int n = 0; n < 8; ++n) {
          short8x bk = *(const short8x*)&Ks[kkd * 4096 + (n * 16 + c16) * 32 + cbp];
          s[n] = __builtin_amdgcn_mfma_f32_16x16x32_bf16(a_q[i][kkd], bk, s[n], 0, 0, 0);
        }

      // p = exp2(s); packed b32 writes, permuted k
#pragma unroll
      for (int r = 0; r < 4; ++r) {
#pragma unroll
        for (int j = 0; j < 4; ++j) {
          uint32 u0 = (uint32)f2b(exp2f(s[2 * j][r]));
          uint32 u1 = (uint32)f2b(exp2f(s[2 * j + 1][r]));
          *(uint32*)&Ps[(((wave * 4 + j) * 16) + (quad * 4 + r)) * 40 + c16 * 2] =
              u0 | (u1 << 16);
        }
      }

      // o += P @ V ; l += P @ ones
#pragma unroll
      for (int kk = 0; kk < 4; ++kk) {
        short8x ap = *(const short8x*)&Ps[(((wave * 4 + kk) * 16) + c16) * 40 + quad * 8];
#pragma unroll
        for (int n = 0; n < 4; ++n) {
          short8x bv = *(const short8x*)&Vs[kk * 2048 + (n * 16 + c16) * 32 + cbp];
          o[i][n] = __builtin_amdgcn_mfma_f32_16x16x32_bf16(ap, bv, o[i][n], 0, 0, 0);
        }
        ol[i] = __builtin_amdgcn_mfma_f32_16x16x32_bf16(ap, ones, ol[i], 0, 0, 0);
      }
    }
    __syncthreads();
  }

  // finalize: w = o/l, per-head rt coef; write bf16 tangent IN PLACE
#pragma unroll
  for (int i = 0; i < 2; ++i)
#pragma unroll
    for (int r = 0; r < 4; ++r) {
      float invl = 1.0f / ol[i][r];
      float w[4];
      float pssq = 0.f;
#pragma unroll
      for (int n = 0; n < 4; ++n) { w[n] = o[i][n][r] * invl; pssq += w[n] * w[n]; }
      float ssq = redSum16(pssq);
      float coef = roundtrip_scale(sqrtf(ssq)) * ratio2;
      int row = b * kS + q0 + wq + i * 16 + quad * 4 + r;
#pragma unroll
      for (int n = 0; n < 4; ++n)
        qb[(size_t)row * kD + h * kHD + n * 16 + c16] = f2b(coef * w[n]);
    }
}

// ---------------- row norm -> roundtrip scale (read-only pass) ----------------
template <int WIDTH>
__global__ __launch_bounds__(256) void k_rowscale(const ushort16* __restrict__ p,
                                                  float* __restrict__ s) {
  __shared__ float sred[4];
  constexpr int PER = WIDTH / 1024;
  size_t base = (size_t)blockIdx.x * WIDTH;
  float ss = 0.f;
#pragma unroll
  for (int i = 0; i < PER; ++i) {
    float v[4];
    load_b4(p + base + i * 1024 + threadIdx.x * 4, v);
    ss += v[0] * v[0] + v[1] * v[1] + v[2] * v[2] + v[3] * v[3];
  }
  ss = blockReduceSum256(ss, sred);
  if (threadIdx.x == 0) s[blockIdx.x] = roundtrip_scale(sqrtf(ss));
}

// ---------------- mobius epilogue core ----------------
__device__ __forceinline__ void mobius_body(float xv[4], float tv[4],
                                            const float* gp, int d4,
                                            float* sred, float outv[4]) {
  float ss = tv[0] * tv[0] + tv[1] * tv[1] + tv[2] * tv[2] + tv[3] * tv[3];
  ss = blockReduceSum256(ss, sred);
  float s5 = roundtrip_scale(sqrtf(ss));
  float gv[4];
  *(float4*)gv = *(const float4*)&gp[d4];
  float at2 = 0.f;
#pragma unroll
  for (int i = 0; i < 4; ++i) {
    float a = gv[i] * s5 * tv[i];
    tv[i] = a;
    at2 += a * a;
  }
  at2 = blockReduceSum256(at2, sred);
  float nyraw = sqrtf(at2);
  float sy = expmap0_scale(nyraw);
  float ynorm = sy * nyraw;
  float y2 = ynorm * ynorm;
  float x2p = 0.f, xyp = 0.f;
#pragma unroll
  for (int i = 0; i < 4; ++i) {
    float y = sy * tv[i];
    tv[i] = y;
    x2p += xv[i] * xv[i];
    xyp += xv[i] * y;
  }
  float x2 = blockReduceSum256(x2p, sred);
  float xy = blockReduceSum256(xyp, sred);
  float cx = 1.0f + 2.0f * xy + y2;
  float cy = 1.0f - x2;
  float den = fmaxf(1.0f + 2.0f * xy + x2 * y2, EPSF);
  float invden = 1.0f / den;
#pragma unroll
  for (int i = 0; i < 4; ++i) outv[i] = (cx * xv[i] + cy * tv[i]) * invden;
}

// final epilogue: out = mobius(xres, expmap0(g*rt(p0 + p1b)))  (p1b bf16)
__global__ __launch_bounds__(256) void k_epilogue2(const float* __restrict__ xres,
                                                   const float* __restrict__ ot0,
                                                   const ushort16* __restrict__ ot1b,
                                                   const float* __restrict__ ada,
                                                   int g_off,
                                                   float* __restrict__ out) {
  __shared__ float sred[4];
  int tok = blockIdx.x;
  int b = tok >> 10;
  size_t base = (size_t)tok * kD;
  int d4 = threadIdx.x * 4;
  float xv[4], tv[4], t1[4];
  *(float4*)tv = *(const float4*)&ot0[base + d4];
  load_b4(ot1b + base + d4, t1);
  *(float4*)xv = *(const float4*)&xres[base + d4];
#pragma unroll
  for (int i = 0; i < 4; ++i) tv[i] += t1[i];
  float outv[4];
  mobius_body(xv, tv, ada + b * 6 * kD + g_off, d4, sred, outv);
  *(float4*)&out[base + d4] = *(float4*)outv;
}

// fused: x_mid = mobius(x, msa partials) -> xmid_out (f32), then prenorm(mlp) -> bf16
__global__ __launch_bounds__(256) void k_epi_pre(const float* __restrict__ xres,
                                                 const float* __restrict__ ot0,
                                                 const ushort16* __restrict__ ot1b,
                                                 const float* __restrict__ ada,
                                                 float* __restrict__ xmid_out,
                                                 ushort16* __restrict__ lx2_out) {
  __shared__ float sred[4];
  int tok = blockIdx.x;
  int b = tok >> 10;
  size_t base = (size_t)tok * kD;
  int d4 = threadIdx.x * 4;
  float xv[4], tv[4], t1[4];
  *(float4*)tv = *(const float4*)&ot0[base + d4];
  load_b4(ot1b + base + d4, t1);
  *(float4*)xv = *(const float4*)&xres[base + d4];
#pragma unroll
  for (int i = 0; i < 4; ++i) tv[i] += t1[i];
  float xm[4];
  mobius_body(xv, tv, ada + b * 6 * kD + 2 * kD, d4, sred, xm);
  *(float4*)&xmid_out[base + d4] = *(float4*)xm;

  float ss = xm[0] * xm[0] + xm[1] * xm[1] + xm[2] * xm[2] + xm[3] * xm[3];
  ss = blockReduceSum256(ss, sred);
  float sl = logmap0_scale(sqrtf(ss));
  float sum = 0.f;
#pragma unroll
  for (int i = 0; i < 4; ++i) { xm[i] *= sl; sum += xm[i]; }
  sum = blockReduceSum256(sum, sred);
  float mean = sum * (1.0f / kD);
  float vs = 0.f;
#pragma unroll
  for (int i = 0; i < 4; ++i) { xm[i] -= mean; vs += xm[i] * xm[i]; }
  vs = blockReduceSum256(vs, sred);
  float inv = rsqrtf(vs * (1.0f / kD) + 1e-6f);
  float shv[4], scv[4];
  *(float4*)shv = *(const float4*)&ada[b * 6 * kD + 3 * kD + d4];
  *(float4*)scv = *(const float4*)&ada[b * 6 * kD + 4 * kD + d4];
  float uu = 0.f;
#pragma unroll
  for (int i = 0; i < 4; ++i) {
    float u = xm[i] * inv * (1.0f + scv[i]) + shv[i];
    xm[i] = u;
    uu += u * u;
  }
  uu = blockReduceSum256(uu, sred);
  float s = roundtrip_scale(sqrtf(uu));
#pragma unroll
  for (int i = 0; i < 4; ++i) xm[i] *= s;
  store_b4(lx2_out + base + d4, xm);
}

// ---------------------------------------------------------------------------
extern "C" void kernel_launch(void* const* d_in, const int* in_sizes, int n_in,
                              void* d_out, int out_size, void* d_ws, size_t ws_size,
                              hipStream_t stream) {
  const float* x     = (const float*)d_in[0];
  const float* t_emb = (const float*)d_in[1];
  const float* w_q = (const float*)d_in[2];  const float* b_q = (const float*)d_in[3];
  const float* w_k = (const float*)d_in[4];  const float* b_k = (const float*)d_in[5];
  const float* w_v = (const float*)d_in[6];  const float* b_v = (const float*)d_in[7];
  const float* w_o = (const float*)d_in[8];  const float* b_o = (const float*)d_in[9];
  const float* w_f1 = (const float*)d_in[10]; const float* b_f1 = (const float*)d_in[11];
  const float* w_f2 = (const float*)d_in[12]; const float* b_f2 = (const float*)d_in[13];
  const float* w_ada = (const float*)d_in[14]; const float* b_ada = (const float*)d_in[15];
  float* out = (float*)d_out;

  constexpr size_t ND = (size_t)kN * kD;    // 4 M
  constexpr size_t NF = (size_t)kN * kFF;   // 16 M
  constexpr size_t DD = (size_t)kD * kD;    // 1 M

  float* ws   = (float*)d_ws;
  float* ada  = ws;                 // 24576 f32
  float* qt   = ada + 6 * kD * kB;  // ND f32 (split-K partial 0, f32+bias)
  float* kt   = qt + ND;            // ND f32 (rowscale arrays: 4096 floats)
  float* vt   = kt + ND;            // ND f32 (x_mid)
  ushort16* qbA = (ushort16*)(vt + ND);   // ND bf16 (lx / qb / attn-T / lx2)
  ushort16* kb  = qbA + ND;               // ND bf16 (q raw -> vT -> bf16 partial1)
  ushort16* vTb = kb + ND;                // ND bf16 (k raw -> k scaled)
  ushort16* actB = vTb + ND;              // NF bf16 (v raw/scaled; h1)
  ushort16* wqT  = actB + NF;             // DD bf16 each
  ushort16* wkT  = wqT + DD;
  ushort16* wvT  = wkT + DD;
  ushort16* woT  = wvT + DD;
  ushort16* wf1T = woT + DD;              // FF*D
  ushort16* wf2T = wf1T + (size_t)kD * kFF;

  double bn = exp(lgamma(512.0) + lgamma(0.5) - lgamma(512.5));
  double bh = exp(lgamma(32.0) + lgamma(0.5) - lgamma(32.5));
  float R1 = (float)(bh / bn);
  float R2 = (float)(bn / bh);

  // 0) weight transposes + cast to bf16 [N][K]
  k_transpose4<<<dim3(16, 16, 4), 256, 0, stream>>>(w_q, w_k, w_v, w_o,
                                                    wqT, wkT, wvT, woT);
  k_transpose_bf16<<<dim3(64, 16), 256, 0, stream>>>(w_f1, wf1T, kD, kFF);
  k_transpose_bf16<<<dim3(16, 64), 256, 0, stream>>>(w_f2, wf2T, kFF, kD);
  // 1) ada
  k_ada<<<dim3(6 * kD / 64, kB), 256, 0, stream>>>(t_emb, w_ada, b_ada, ada);
  // 2) prenorm (msa): lx -> qbA (bf16)
  k_prenorm<<<kN, 256, 0, stream>>>(x, ada, 0 * kD, 1 * kD, qbA);
  // 3) q,k,v projections, bf16 out: q->kb, k->vTb, v->actB
  k_gemm_bf16<1, 1><<<dim3(kN / 128, kD / 128, 3), 256, 0, stream>>>(
      qbA, wqT, wkT, wvT, b_q, b_k, b_v, nullptr, kb, vTb, actB, kN, kD, kD);
  // 4) head split: qb->qbA (pre-scaled 0.125*log2e), k in vTb, v in actB
  k_headsplit_b<<<kN, 256, 0, stream>>>(kb, vTb, actB, qbA, R1);
  // 5) V transpose (k-permuted): actB -> kb
  k_vtrans_b<<<dim3(kS / 64, kB * kH), 256, 0, stream>>>(actB, kb);
  // 6) attention (max-free): reads qbA, writes bf16 tangent T in place
  k_attn_mfma<<<dim3(kB * kH, kS / 128), 256, 0, stream>>>(qbA, vTb, kb, R2);
  // 7) row scales for the concat-roundtrip: s[tok] from |T| -> kt
  k_rowscale<kD><<<kN, 256, 0, stream>>>(qbA, kt);
  // 8) o projection, split-K=2, row-scaled: partials qt (f32,+bias), kb (bf16)
  k_gemm_bf16<0, 2><<<dim3(kN / 128, kD / 128, 2), 256, 0, stream>>>(
      qbA, woT, woT, woT, b_o, b_o, b_o, kt, qt, kb, nullptr, kN, kD, kD);
  // 9+10) fused mobius epilogue (msa) + prenorm (mlp): vt <- x_mid, qbA <- lx2
  k_epi_pre<<<kN, 256, 0, stream>>>(x, qt, kb, ada, vt, qbA);
  // 11) f1 -> actB (raw h1, bf16)
  k_gemm_bf16<1, 1><<<dim3(kN / 128, kFF / 128, 1), 256, 0, stream>>>(
      qbA, wf1T, wf1T, wf1T, b_f1, b_f1, b_f1, nullptr, actB, actB, actB, kN, kFF, kD);
  // 12) row scales for rt(h1) -> kt
  k_rowscale<kFF><<<kN, 256, 0, stream>>>(actB, kt);
  // 13) f2, split-K=2, row-scaled: partials qt (f32,+bias), kb (bf16)
  k_gemm_bf16<0, 2><<<dim3(kN / 128, kD / 128, 2), 256, 0, stream>>>(
      actB, wf2T, wf2T, wf2T, b_f2, b_f2, b_f2, kt, qt, kb, nullptr, kN, kD, kFF);
  // 14) mobius epilogue (mlp): out = mobius(vt, qt + kb)
  k_epilogue2<<<kN, 256, 0, stream>>>(vt, qt, kb, ada, 5 * kD, out);

  (void)in_sizes; (void)n_in; (void)out_size; (void)ws_size;
}